// Round 2
// baseline (13982.162 us; speedup 1.0000x reference)
//
#include <hip/hip_runtime.h>
#include <math.h>

// ===================== JAX Threefry-2x32 (bit-exact) =====================
__device__ __forceinline__ void threefry2x32(unsigned k0, unsigned k1,
                                             unsigned x0, unsigned x1,
                                             unsigned& o0, unsigned& o1)
{
  unsigned ks2 = k0 ^ k1 ^ 0x1BD11BDAu;
  x0 += k0; x1 += k1;
#define TFR(r) { x0 += x1; x1 = (x1 << r) | (x1 >> (32 - r)); x1 ^= x0; }
  TFR(13) TFR(15) TFR(26) TFR(6)
  x0 += k1;  x1 += ks2 + 1u;
  TFR(17) TFR(29) TFR(16) TFR(24)
  x0 += ks2; x1 += k0 + 2u;
  TFR(13) TFR(15) TFR(26) TFR(6)
  x0 += k0;  x1 += k1 + 3u;
  TFR(17) TFR(29) TFR(16) TFR(24)
  x0 += k1;  x1 += ks2 + 4u;
  TFR(13) TFR(15) TFR(26) TFR(6)
  x0 += ks2; x1 += k0 + 5u;
#undef TFR
  o0 = x0; o1 = x1;
}

// jax_threefry_partitionable=True (default since jax 0.4.36):
// 32-bit word e of random_bits = o0 ^ o1 of block (x0=hi64(e)=0, x1=e)
__device__ __forceinline__ unsigned rand_word(unsigned kA, unsigned kB, unsigned e)
{
  unsigned o0, o1;
  threefry2x32(kA, kB, 0u, e, o0, o1);
  return o0 ^ o1;
}

__device__ __forceinline__ float bits_to_unit(unsigned bits)
{
  unsigned u = (bits >> 9) | 0x3f800000u;
  return __uint_as_float(u) - 1.0f;   // exact, in [0,1)
}

// erfinv in double: Giles poly init + 2 Newton iterations on erf()
__device__ __forceinline__ double erfinv_d(double x)
{
  double w = -log((1.0 - x) * (1.0 + x));
  double p;
  if (w < 5.0) {
    w -= 2.5;
    p = 2.81022636e-08;
    p = fma(p, w, 3.43273939e-07);
    p = fma(p, w, -3.5233877e-06);
    p = fma(p, w, -4.39150654e-06);
    p = fma(p, w, 0.00021858087);
    p = fma(p, w, -0.00125372503);
    p = fma(p, w, -0.00417768164);
    p = fma(p, w, 0.246640727);
    p = fma(p, w, 1.50140941);
  } else {
    w = sqrt(w) - 3.0;
    p = -0.000200214257;
    p = fma(p, w, 0.000100950558);
    p = fma(p, w, 0.00134934322);
    p = fma(p, w, -0.00367342844);
    p = fma(p, w, 0.00573950773);
    p = fma(p, w, -0.0076224613);
    p = fma(p, w, 0.00943887047);
    p = fma(p, w, 1.00167406);
    p = fma(p, w, 2.83297682);
  }
  double r = p * x;
  #pragma unroll
  for (int it = 0; it < 2; ++it) {
    double err = erf(r) - x;
    r = r - 0.8862269254527580136 * err * exp(r * r);   // sqrt(pi)/2
  }
  return r;
}

// N(0,1) sample e of a jax.random.normal(f32) draw
__device__ __forceinline__ double eps_normal(unsigned kA, unsigned kB, unsigned e)
{
  float f = bits_to_unit(rand_word(kA, kB, e));
  // u = f*(hi-lo)+lo with lo = -(1-2^-24), hi = 1  (computed in f64)
  double u = (double)f * (2.0 - 5.9604644775390625e-8)
           - (1.0 - 5.9604644775390625e-8);
  return 1.4142135623730951 * erfinv_d(u);
}

__device__ __forceinline__ double sigd(double x) { return 1.0 / (1.0 + exp(-x)); }

// ===================== setup kernels =====================
__global__ void k_keys(unsigned* keys)
{
  if (threadIdx.x != 0 || blockIdx.x != 0) return;
  // partitionable/foldlike split: key_i = (o0,o1) of block (0, i)
  unsigned a0,a1,b0,b1,c0,c1,d0,d1;
  unsigned kx = 0u, ky = 42u;                 // jax.random.key(42)
  // key, k0 = split(key)
  threefry2x32(kx, ky, 0u, 0u, a0, a1);       // new carried key
  threefry2x32(kx, ky, 0u, 1u, b0, b1);       // k0 (for h0 uniform)
  keys[0] = b0; keys[1] = b1;
  kx = a0; ky = a1;
  for (int s = 0; s < 100; ++s) {
    // k, ke, kr = split(k, 3): blocks (0,0), (0,1), (0,2)
    threefry2x32(kx, ky, 0u, 0u, a0, a1);     // k
    threefry2x32(kx, ky, 0u, 1u, c0, c1);     // ke
    threefry2x32(kx, ky, 0u, 2u, d0, d1);     // kr
    keys[2 + 4*s + 0] = c0; keys[2 + 4*s + 1] = c1;   // ke
    keys[2 + 4*s + 2] = d0; keys[2 + 4*s + 3] = d1;   // kr
    kx = a0; ky = a1;                                  // carried k
  }
}

__global__ __launch_bounds__(256) void k_prep(
    const float* fcz_w, const float* fcz_b, const float* fcr_w, const float* fcr_b,
    const float* fcn_w, const float* fcn_b, const float* fco_w, const float* fco_b,
    const float* h2l_w, const float* h2l_b,
    double* wzrT, double* wnT, double* wo, double* bz, double* br,
    double* bnn, double* bo, double* h2lw, double* h2lb)
{
  int id = blockIdx.x * 256 + threadIdx.x;
  if (id < 65536) {
    int k = id >> 8, j = id & 255;
    wzrT[id] = (double)((j < 128) ? fcz_w[j*256 + k] : fcr_w[(j-128)*256 + k]);
    return;
  }
  id -= 65536;
  if (id < 65536) { int k = id >> 8, j = id & 255; wnT[id] = (double)fcn_w[j*256 + k]; return; }
  id -= 65536;
  if (id < 256) { wo[id] = (double)fco_w[id]; return; }
  id -= 256;
  if (id < 128) { bz[id] = (double)fcz_b[id]; return; }
  id -= 128;
  if (id < 128) { br[id] = (double)fcr_b[id]; return; }
  id -= 128;
  if (id < 256) { bnn[id] = (double)fcn_b[id]; return; }
  id -= 256;
  if (id < 1) { bo[0] = (double)fco_b[0]; return; }
  id -= 1;
  if (id < 384) { h2lw[id] = (double)h2l_w[id]; return; }
  id -= 384;
  if (id < 3) { h2lb[id] = (double)h2l_b[id]; return; }
}

__global__ __launch_bounds__(256) void k_h0(const unsigned* keys, double* h, double* p)
{
  unsigned e = blockIdx.x * 256 + threadIdx.x;    // < 524288
  h[e] = (double)bits_to_unit(rand_word(keys[0], keys[1], e));
  if (e < 4096) p[e] = (double)(float)log(1.0 / 128.0);   // f32-rounded p0
}

// ===================== frontend (map CNN encoder) =====================
__global__ __launch_bounds__(256) void k_conv1(const float* in, const float* w, double* out)
{
  int bc = blockIdx.x; int b = bc >> 4, co = bc & 15;
  __shared__ double wl[25];
  if (threadIdx.x < 25) wl[threadIdx.x] = (double)w[co*25 + threadIdx.x];
  __syncthreads();
  const float* ib = in + (size_t)b * 4096;
  for (int px = threadIdx.x; px < 1024; px += 256) {
    int oh = px >> 5, ow = px & 31;
    double acc = 0.0;
    for (int kh = 0; kh < 5; ++kh) {
      int ih = oh*2 - 2 + kh; if (ih < 0 || ih >= 64) continue;
      for (int kw = 0; kw < 5; ++kw) {
        int iw = ow*2 - 2 + kw; if (iw < 0 || iw >= 64) continue;
        acc = fma((double)ib[ih*64 + iw], wl[kh*5 + kw], acc);
      }
    }
    out[((size_t)b*16 + co)*1024 + px] = fmax(acc, 0.0);   // relu
  }
}

__global__ __launch_bounds__(256) void k_conv3x3(const double* in, const float* w,
                                                 double* out, int Ci, int Co)
{
  int bc = blockIdx.x; int b = bc / Co, co = bc % Co;
  __shared__ double wl[288];
  for (int e = threadIdx.x; e < Ci*9; e += 256) wl[e] = (double)w[co*Ci*9 + e];
  __syncthreads();
  const double* ib = in + (size_t)b * Ci * 1024;
  for (int px = threadIdx.x; px < 1024; px += 256) {
    int oh = px >> 5, ow = px & 31;
    double acc = 0.0;
    for (int ci = 0; ci < Ci; ++ci) {
      const double* ip = ib + ci*1024;
      const double* wp = wl + ci*9;
      for (int kh = 0; kh < 3; ++kh) {
        int ih = oh - 1 + kh; if (ih < 0 || ih >= 32) continue;
        for (int kw = 0; kw < 3; ++kw) {
          int iw = ow - 1 + kw; if (iw < 0 || iw >= 32) continue;
          acc = fma(ip[ih*32 + iw], wp[kh*3 + kw], acc);
        }
      }
    }
    out[((size_t)b*Co + co)*1024 + px] = fmax(acc, 0.0);
  }
}

__global__ __launch_bounds__(256) void k_bnstats(const double* x, const float* g,
                                                 const float* bta, double* scsh, int C)
{
  int c = blockIdx.x;
  double s = 0.0, s2 = 0.0;
  for (int e = threadIdx.x; e < 32*1024; e += 256) {
    int b = e >> 10, px = e & 1023;
    double v = x[((size_t)b*C + c)*1024 + px];
    s += v; s2 = fma(v, v, s2);
  }
  __shared__ double rs[256], rs2[256];
  rs[threadIdx.x] = s; rs2[threadIdx.x] = s2;
  __syncthreads();
  for (int d = 128; d; d >>= 1) {
    if (threadIdx.x < d) { rs[threadIdx.x] += rs[threadIdx.x + d]; rs2[threadIdx.x] += rs2[threadIdx.x + d]; }
    __syncthreads();
  }
  if (threadIdx.x == 0) {
    double n = 32768.0;
    double mean = rs[0] / n;
    double var = rs2[0] / n - mean*mean;
    double sc = (double)g[c] / sqrt(var + 1e-5);
    scsh[c*2] = sc;
    scsh[c*2 + 1] = (double)bta[c] - mean * sc;
  }
}

__global__ __launch_bounds__(256) void k_bnapply(double* x, const double* scsh, int C)
{
  size_t e = (size_t)blockIdx.x * 256 + threadIdx.x;   // < 32*C*1024
  int c = (int)((e >> 10) % (size_t)C);
  x[e] = fma(x[e], scsh[c*2], scsh[c*2 + 1]);
}

__global__ __launch_bounds__(256) void k_mapfc(const double* x, const float* w,
                                               const float* bias, double* emb)
{
  int blk = blockIdx.x; int b = blk >> 4, jg = blk & 15;
  double acc[8];
  #pragma unroll
  for (int jj = 0; jj < 8; ++jj) acc[jj] = 0.0;
  const double* xb = x + (size_t)b * 32768;
  for (int e = threadIdx.x; e < 32768; e += 256) {
    double xv = xb[e];
    #pragma unroll
    for (int jj = 0; jj < 8; ++jj)
      acc[jj] = fma(xv, (double)w[(size_t)(jg*8 + jj)*32768 + e], acc[jj]);
  }
  __shared__ double red[8][256];
  #pragma unroll
  for (int jj = 0; jj < 8; ++jj) red[jj][threadIdx.x] = acc[jj];
  __syncthreads();
  for (int d = 128; d; d >>= 1) {
    if (threadIdx.x < d)
      #pragma unroll
      for (int jj = 0; jj < 8; ++jj) red[jj][threadIdx.x] += red[jj][threadIdx.x + d];
    __syncthreads();
  }
  if (threadIdx.x < 8) {
    int j = jg*8 + threadIdx.x;
    emb[b*128 + j] = fmax(red[threadIdx.x][0] + (double)bias[j], 0.0);
  }
}

__global__ void k_maps(const double* emb, const float* m2o_w, const float* m2o_b,
                       const float* m2a_w, const float* m2a_b,
                       double* omap, double* amap)
{
  int b = blockIdx.x, j = threadIdx.x;   // 64 threads
  double a1 = (double)m2o_b[j], a2 = (double)m2a_b[j];
  for (int k = 0; k < 128; ++k) {
    double ev = emb[b*128 + k];
    a1 = fma(ev, (double)m2o_w[j*128 + k], a1);
    a2 = fma(ev, (double)m2a_w[j*128 + k], a2);
  }
  omap[b*64 + j] = fmax(a1, 0.0);
  amap[b*64 + j] = fmax(a2, 0.0);
}

__global__ __launch_bounds__(128) void k_xs(const float* obs_in, const float* act_in,
                                            const float* obs_w, const float* obs_b,
                                            const float* act_w, const float* act_b,
                                            const double* omap, const double* amap,
                                            double* xs)
{
  int s = blockIdx.x, b = blockIdx.y, j = threadIdx.x;
  double v;
  if (j < 64) {
    double a = (double)obs_b[j];
    const float* o = obs_in + ((size_t)b*100 + s)*16;
    for (int k = 0; k < 16; ++k) a = fma((double)o[k], (double)obs_w[j*16 + k], a);
    v = fmax(a, 0.0) * omap[b*64 + j];
  } else {
    int j2 = j - 64;
    double a = (double)act_b[j2];
    const float* o = act_in + ((size_t)b*100 + s)*3;
    for (int k = 0; k < 3; ++k) a = fma((double)o[k], (double)act_w[j2*3 + k], a);
    v = fmax(a, 0.0) * amap[b*64 + j2];
  }
  xs[((size_t)s*32 + b)*128 + j] = v;
}

// ===================== per-step scan kernels =====================
// K1: z, rg = sigmoid([x|h] @ Wzr^T + b).  8 rows/block, 128 thr, 2 outs/thr.
__global__ __launch_bounds__(128) void k_zr(const double* __restrict__ h,
    const double* __restrict__ xs_s, const double* __restrict__ wT,
    const double* __restrict__ bz, const double* __restrict__ br,
    double* __restrict__ z, double* __restrict__ rg)
{
  __shared__ double a[8][256];
  const int t = threadIdx.x;
  const int r0 = blockIdx.x * 8;
  for (int e = t; e < 2048; e += 128) {
    int i = e >> 8, k = e & 255;
    int r = r0 + i, b = r & 31;
    a[i][k] = (k < 128) ? xs_s[b*128 + k] : h[(size_t)r*128 + (k - 128)];
  }
  __syncthreads();
  double acc0[8], acc1[8];
  #pragma unroll
  for (int i = 0; i < 8; ++i) { acc0[i] = 0.0; acc1[i] = 0.0; }
  for (int k = 0; k < 256; ++k) {
    double w0 = wT[k*256 + t];
    double w1 = wT[k*256 + t + 128];
    #pragma unroll
    for (int i = 0; i < 8; ++i) {
      double av = a[i][k];
      acc0[i] = fma(av, w0, acc0[i]);
      acc1[i] = fma(av, w1, acc1[i]);
    }
  }
  double b0v = bz[t], b1v = br[t];
  #pragma unroll
  for (int i = 0; i < 8; ++i) {
    int r = r0 + i;
    z [(size_t)r*128 + t] = sigd(acc0[i] + b0v);
    rg[(size_t)r*128 + t] = sigd(acc1[i] + b1v);
  }
}

// K2: n_pre = [rg*h|x] @ Wn^T + b;  n = mu + eps*softplus(var);
//     h1 = (1-z)*n + z*h;  logpdf = [h1|x].wo + bo + p
__global__ __launch_bounds__(128) void k_n(const double* __restrict__ h,
    const double* __restrict__ xs_s, const double* __restrict__ z,
    const double* __restrict__ rg, const double* __restrict__ wT,
    const double* __restrict__ bnn, const double* __restrict__ wo,
    const double* __restrict__ bo, const double* __restrict__ p,
    double* __restrict__ h1, double* __restrict__ logpdf,
    const unsigned* __restrict__ keys, int s)
{
  __shared__ double a[8][256];
  const int t = threadIdx.x;
  const int r0 = blockIdx.x * 8;
  for (int e = t; e < 2048; e += 128) {
    int i = e >> 8, k = e & 255;
    int r = r0 + i, b = r & 31;
    a[i][k] = (k < 128) ? rg[(size_t)r*128 + k] * h[(size_t)r*128 + k]
                        : xs_s[b*128 + (k - 128)];
  }
  __syncthreads();
  double acc0[8], acc1[8];
  #pragma unroll
  for (int i = 0; i < 8; ++i) { acc0[i] = 0.0; acc1[i] = 0.0; }
  for (int k = 0; k < 256; ++k) {
    double w0 = wT[k*256 + t];
    double w1 = wT[k*256 + t + 128];
    #pragma unroll
    for (int i = 0; i < 8; ++i) {
      double av = a[i][k];
      acc0[i] = fma(av, w0, acc0[i]);   // mu col t
      acc1[i] = fma(av, w1, acc1[i]);   // var col t
    }
  }
  __syncthreads();   // done reading a[ ][k<128]; safe to overwrite with h1
  unsigned keA = keys[2 + 4*s], keB = keys[2 + 4*s + 1];
  double b0v = bnn[t], b1v = bnn[t + 128];
  #pragma unroll
  for (int i = 0; i < 8; ++i) {
    int r = r0 + i;
    double mu  = acc0[i] + b0v;
    double var = acc1[i] + b1v;
    double epsn = eps_normal(keA, keB, (unsigned)(r*128 + t));
    double sp = fmax(var, 0.0) + log1p(exp(-fabs(var)));   // softplus
    double n  = fma(epsn, sp, mu);
    double zz = z[(size_t)r*128 + t];
    double hh = h[(size_t)r*128 + t];
    double hv = (1.0 - zz)*n + zz*hh;
    h1[(size_t)r*128 + t] = hv;
    a[i][t] = hv;                 // keep h1 in LDS; a[ ][128..255] still holds x
  }
  __syncthreads();
  int row = t >> 4, l16 = t & 15;   // 8 rows x 16 lanes
  double part = 0.0;
  for (int k = l16; k < 256; k += 16) part = fma(a[row][k], wo[k], part);
  for (int d = 8; d; d >>= 1) part += __shfl_xor(part, d, 16);
  if (l16 == 0) logpdf[r0 + row] = part + bo[0] + p[r0 + row];
}

// K3: per-batch log_softmax over particles + resampling logits
__global__ __launch_bounds__(128) void k_softmax(const double* logpdf,
                                                 double* p1, double* lg)
{
  int b = blockIdx.x, i = threadIdx.x;
  double v = logpdf[i*32 + b];
  __shared__ double sm[2], ss[2];
  double m = v;
  for (int d = 32; d; d >>= 1) m = fmax(m, __shfl_xor(m, d, 64));
  if ((i & 63) == 0) sm[i >> 6] = m;
  __syncthreads();
  m = fmax(sm[0], sm[1]);
  double e = exp(v - m), s = e;
  for (int d = 32; d; d >>= 1) s += __shfl_xor(s, d, 64);
  if ((i & 63) == 0) ss[i >> 6] = s;
  __syncthreads();
  double p1v = v - m - log(ss[0] + ss[1]);
  p1[i*32 + b] = p1v;
  lg[i*32 + b] = log(0.5*exp(p1v) + 0.00390625);   // (1-alpha)/P
}

// K4a: Gumbel-argmax categorical draw (first-index tie-break) + pn_pre
__global__ __launch_bounds__(128) void k_resample(const double* __restrict__ lg,
    const double* __restrict__ p1, const unsigned* __restrict__ keys, int s,
    int* __restrict__ idx, double* __restrict__ pn_pre)
{
  int r = blockIdx.x, j = threadIdx.x;
  int b = r & 31;
  unsigned kA = keys[2 + 4*s + 2], kB = keys[2 + 4*s + 3];
  unsigned bits = rand_word(kA, kB, (unsigned)(r*128 + j));
  float f = bits_to_unit(bits);
  double u = (f == 0.0f) ? 1.1754943508222875e-38 : (double)f;
  double val = -log(-log(u)) + lg[j*32 + b];
  int bj = j;
  for (int d = 32; d; d >>= 1) {
    double ov = __shfl_xor(val, d, 64);
    int    oj = __shfl_xor(bj, d, 64);
    if (ov > val || (ov == val && oj < bj)) { val = ov; bj = oj; }
  }
  __shared__ double sv[2]; __shared__ int sj[2];
  if ((j & 63) == 0) { sv[j >> 6] = val; sj[j >> 6] = bj; }
  __syncthreads();
  if (j == 0) {
    int best = (sv[1] > sv[0] || (sv[1] == sv[0] && sj[1] < sj[0])) ? sj[1] : sj[0];
    idx[r] = best;
    double pe = exp(p1[best*32 + b]);
    pn_pre[r] = log(pe / (0.5*pe + 0.00390625));
  }
}

// K4b: gather resampled particles into the live state
__global__ __launch_bounds__(256) void k_gather(const double* __restrict__ h1,
                                                const int* __restrict__ idx,
                                                double* __restrict__ hst)
{
  int tid = blockIdx.x * 256 + threadIdx.x;   // < 524288
  int r = tid >> 7, c = tid & 127;
  int b = r & 31;
  hst[tid] = h1[((size_t)(idx[r]*32 + b))*128 + c];
}

// K5: normalize pn, update carry p, exp-weighted particle mean -> y[s]
__global__ __launch_bounds__(128) void k_final(const double* __restrict__ pn_pre,
    const double* __restrict__ hst, const double* __restrict__ h2lw,
    const double* __restrict__ h2lb, double* __restrict__ p,
    float* __restrict__ yout, int s)
{
  int b = blockIdx.x, i = threadIdx.x;
  double q = pn_pre[i*32 + b];
  __shared__ double sm[2], ss[2], w[128], ys[128];
  double m = q;
  for (int d = 32; d; d >>= 1) m = fmax(m, __shfl_xor(m, d, 64));
  if ((i & 63) == 0) sm[i >> 6] = m;
  __syncthreads();
  m = fmax(sm[0], sm[1]);
  double e = exp(q - m), ssum = e;
  for (int d = 32; d; d >>= 1) ssum += __shfl_xor(ssum, d, 64);
  if ((i & 63) == 0) ss[i >> 6] = ssum;
  __syncthreads();
  double pn = q - (m + log(ss[0] + ss[1]));
  p[i*32 + b] = pn;
  w[i] = exp(pn);
  __syncthreads();
  double acc = 0.0;
  for (int ii = 0; ii < 128; ++ii)
    acc = fma(w[ii], hst[(size_t)(ii*32 + b)*128 + i], acc);
  ys[i] = acc;
  __syncthreads();
  if (i < 3) {
    double d = h2lb[i];
    for (int c = 0; c < 128; ++c) d = fma(h2lw[i*128 + c], ys[c], d);
    yout[s*96 + b*3 + i] = (float)(1.0 / (1.0 + exp(-d)));
  }
}

// K6: pf[s] = sigmoid(h2l(h_new)) — wave per row
__global__ __launch_bounds__(256) void k_pf(const double* __restrict__ hst,
    const double* __restrict__ h2lw, const double* __restrict__ h2lb,
    float* __restrict__ pfout, int s)
{
  int wv = threadIdx.x >> 6, lane = threadIdx.x & 63;
  int r = blockIdx.x * 4 + wv;
  const double* hr = hst + (size_t)r * 128;
  double v0 = hr[lane*2], v1 = hr[lane*2 + 1];
  double s0 = fma(v0, h2lw[lane*2],       v1 * h2lw[lane*2 + 1]);
  double s1 = fma(v0, h2lw[128 + lane*2], v1 * h2lw[128 + lane*2 + 1]);
  double s2 = fma(v0, h2lw[256 + lane*2], v1 * h2lw[256 + lane*2 + 1]);
  for (int d = 32; d; d >>= 1) {
    s0 += __shfl_xor(s0, d, 64);
    s1 += __shfl_xor(s1, d, 64);
    s2 += __shfl_xor(s2, d, 64);
  }
  if (lane == 0) {
    float* o = pfout + (size_t)s * 12288 + r * 3;
    o[0] = (float)(1.0 / (1.0 + exp(-(s0 + h2lb[0]))));
    o[1] = (float)(1.0 / (1.0 + exp(-(s1 + h2lb[1]))));
    o[2] = (float)(1.0 / (1.0 + exp(-(s2 + h2lb[2]))));
  }
}

// ===================== host launch =====================
extern "C" void kernel_launch(void* const* d_in, const int* in_sizes, int n_in,
                              void* d_out, int out_size, void* d_ws, size_t ws_size,
                              hipStream_t stream)
{
  (void)in_sizes; (void)n_in; (void)out_size; (void)ws_size;
  const float* map_in = (const float*)d_in[0];
  const float* obs_in = (const float*)d_in[1];
  const float* act_in = (const float*)d_in[2];
  const float* c1_w = (const float*)d_in[3];
  const float* c1_g = (const float*)d_in[4];
  const float* c1_b = (const float*)d_in[5];
  const float* c2_w = (const float*)d_in[6];
  const float* c2_g = (const float*)d_in[7];
  const float* c2_b = (const float*)d_in[8];
  const float* c3_w = (const float*)d_in[9];
  const float* c3_g = (const float*)d_in[10];
  const float* c3_b = (const float*)d_in[11];
  const float* map_w = (const float*)d_in[12];
  const float* map_b = (const float*)d_in[13];
  const float* m2o_w = (const float*)d_in[14];
  const float* m2o_b = (const float*)d_in[15];
  const float* m2a_w = (const float*)d_in[16];
  const float* m2a_b = (const float*)d_in[17];
  const float* obs_w = (const float*)d_in[18];
  const float* obs_b = (const float*)d_in[19];
  const float* act_w = (const float*)d_in[20];
  const float* act_b = (const float*)d_in[21];
  const float* fcz_w = (const float*)d_in[22];
  const float* fcz_b = (const float*)d_in[23];
  const float* fcr_w = (const float*)d_in[24];
  const float* fcr_b = (const float*)d_in[25];
  const float* fcn_w = (const float*)d_in[26];
  const float* fcn_b = (const float*)d_in[27];
  const float* fco_w = (const float*)d_in[28];
  const float* fco_b = (const float*)d_in[29];
  const float* h2l_w = (const float*)d_in[30];
  const float* h2l_b = (const float*)d_in[31];

  float* yout  = (float*)d_out;
  float* pfout = (float*)d_out + 9600;

  char* ws = (char*)d_ws;
  double*   H      = (double*)(ws + 0);           // 4096*128
  double*   H1     = (double*)(ws + 4194304);
  double*   Z      = (double*)(ws + 8388608);
  double*   RG     = (double*)(ws + 12582912);
  double*   XS     = (double*)(ws + 16777216);    // 100*32*128
  double*   C1O    = (double*)(ws + 20054016);    // 32*16*1024
  double*   C2O    = (double*)(ws + 24248320);    // 32*32*1024
  double*   C3O    = (double*)(ws + 32636928);    // 32*32*1024
  double*   WZRT   = (double*)(ws + 41025536);    // 256*256
  double*   WNT    = (double*)(ws + 41549824);    // 256*256
  double*   WO     = (double*)(ws + 42074112);    // 256
  double*   BZ     = (double*)(ws + 42076160);
  double*   BR     = (double*)(ws + 42077184);
  double*   BNN    = (double*)(ws + 42078208);
  double*   BO     = (double*)(ws + 42080256);
  double*   H2LW   = (double*)(ws + 42080512);
  double*   H2LB   = (double*)(ws + 42083584);
  double*   EMB    = (double*)(ws + 42083840);    // 32*128
  double*   OMAP   = (double*)(ws + 42116608);    // 32*64
  double*   AMAP   = (double*)(ws + 42132992);
  double*   P      = (double*)(ws + 42149376);    // 4096
  double*   P1     = (double*)(ws + 42182144);    // 128*32
  double*   LG     = (double*)(ws + 42214912);
  double*   PNPRE  = (double*)(ws + 42247680);
  double*   LOGPDF = (double*)(ws + 42280448);
  int*      IDX    = (int*)   (ws + 42313216);    // 4096
  unsigned* KEYS   = (unsigned*)(ws + 42329600);  // 402
  double*   SCSH   = (double*)(ws + 42331648);    // 32*2

  // ---- setup ----
  k_keys<<<1, 64, 0, stream>>>(KEYS);
  k_prep<<<517, 256, 0, stream>>>(fcz_w, fcz_b, fcr_w, fcr_b, fcn_w, fcn_b,
                                  fco_w, fco_b, h2l_w, h2l_b,
                                  WZRT, WNT, WO, BZ, BR, BNN, BO, H2LW, H2LB);
  k_h0<<<2048, 256, 0, stream>>>(KEYS, H, P);

  // ---- frontend ----
  k_conv1<<<512, 256, 0, stream>>>(map_in, c1_w, C1O);
  k_bnstats<<<16, 256, 0, stream>>>(C1O, c1_g, c1_b, SCSH, 16);
  k_bnapply<<<2048, 256, 0, stream>>>(C1O, SCSH, 16);
  k_conv3x3<<<1024, 256, 0, stream>>>(C1O, c2_w, C2O, 16, 32);
  k_bnstats<<<32, 256, 0, stream>>>(C2O, c2_g, c2_b, SCSH, 32);
  k_bnapply<<<4096, 256, 0, stream>>>(C2O, SCSH, 32);
  k_conv3x3<<<1024, 256, 0, stream>>>(C2O, c3_w, C3O, 32, 32);
  k_bnstats<<<32, 256, 0, stream>>>(C3O, c3_g, c3_b, SCSH, 32);
  k_bnapply<<<4096, 256, 0, stream>>>(C3O, SCSH, 32);
  k_mapfc<<<512, 256, 0, stream>>>(C3O, map_w, map_b, EMB);
  k_maps<<<32, 64, 0, stream>>>(EMB, m2o_w, m2o_b, m2a_w, m2a_b, OMAP, AMAP);
  {
    dim3 g(100, 32);
    k_xs<<<g, 128, 0, stream>>>(obs_in, act_in, obs_w, obs_b, act_w, act_b,
                                OMAP, AMAP, XS);
  }

  // ---- scan over 100 timesteps ----
  for (int s = 0; s < 100; ++s) {
    const double* xs_s = XS + (size_t)s * 32 * 128;
    k_zr<<<512, 128, 0, stream>>>(H, xs_s, WZRT, BZ, BR, Z, RG);
    k_n<<<512, 128, 0, stream>>>(H, xs_s, Z, RG, WNT, BNN, WO, BO, P,
                                 H1, LOGPDF, KEYS, s);
    k_softmax<<<32, 128, 0, stream>>>(LOGPDF, P1, LG);
    k_resample<<<4096, 128, 0, stream>>>(LG, P1, KEYS, s, IDX, PNPRE);
    k_gather<<<2048, 256, 0, stream>>>(H1, IDX, H);
    k_final<<<32, 128, 0, stream>>>(PNPRE, H, H2LW, H2LB, P, yout, s);
    k_pf<<<1024, 256, 0, stream>>>(H, H2LW, H2LB, pfout, s);
  }
}

// Round 4
// 12140.600 us; speedup vs baseline: 1.1517x; 1.1517x over previous
//
#include <hip/hip_runtime.h>
#include <math.h>

// ===================== JAX Threefry-2x32 (bit-exact) =====================
__device__ __forceinline__ void threefry2x32(unsigned k0, unsigned k1,
                                             unsigned x0, unsigned x1,
                                             unsigned& o0, unsigned& o1)
{
  unsigned ks2 = k0 ^ k1 ^ 0x1BD11BDAu;
  x0 += k0; x1 += k1;
#define TFR(r) { x0 += x1; x1 = (x1 << r) | (x1 >> (32 - r)); x1 ^= x0; }
  TFR(13) TFR(15) TFR(26) TFR(6)
  x0 += k1;  x1 += ks2 + 1u;
  TFR(17) TFR(29) TFR(16) TFR(24)
  x0 += ks2; x1 += k0 + 2u;
  TFR(13) TFR(15) TFR(26) TFR(6)
  x0 += k0;  x1 += k1 + 3u;
  TFR(17) TFR(29) TFR(16) TFR(24)
  x0 += k1;  x1 += ks2 + 4u;
  TFR(13) TFR(15) TFR(26) TFR(6)
  x0 += ks2; x1 += k0 + 5u;
#undef TFR
  o0 = x0; o1 = x1;
}

// jax_threefry_partitionable=True: word e = o0 ^ o1 of block (0, e)
__device__ __forceinline__ unsigned rand_word(unsigned kA, unsigned kB, unsigned e)
{
  unsigned o0, o1;
  threefry2x32(kA, kB, 0u, e, o0, o1);
  return o0 ^ o1;
}

__device__ __forceinline__ float bits_to_unit(unsigned bits)
{
  unsigned u = (bits >> 9) | 0x3f800000u;
  return __uint_as_float(u) - 1.0f;   // exact, in [0,1)
}

// erfinv in double: Giles poly init + 1 Halley iteration on erf()
__device__ __forceinline__ double erfinv_d(double x)
{
  double w = -log((1.0 - x) * (1.0 + x));
  double p;
  if (w < 5.0) {
    w -= 2.5;
    p = 2.81022636e-08;
    p = fma(p, w, 3.43273939e-07);
    p = fma(p, w, -3.5233877e-06);
    p = fma(p, w, -4.39150654e-06);
    p = fma(p, w, 0.00021858087);
    p = fma(p, w, -0.00125372503);
    p = fma(p, w, -0.00417768164);
    p = fma(p, w, 0.246640727);
    p = fma(p, w, 1.50140941);
  } else {
    w = sqrt(w) - 3.0;
    p = -0.000200214257;
    p = fma(p, w, 0.000100950558);
    p = fma(p, w, 0.00134934322);
    p = fma(p, w, -0.00367342844);
    p = fma(p, w, 0.00573950773);
    p = fma(p, w, -0.0076224613);
    p = fma(p, w, 0.00943887047);
    p = fma(p, w, 1.00167406);
    p = fma(p, w, 2.83297682);
  }
  double r = p * x;
  // one Halley step (cubic): q = f/f'; r -= q/(1 + r*q)
  double f  = erf(r) - x;
  double fp = 1.1283791670955126 * exp(-r * r);   // 2/sqrt(pi) e^{-r^2}
  double q  = f / fp;
  return r - q / (1.0 + r * q);
}

// N(0,1) sample e of a jax.random.normal(f32) draw
__device__ __forceinline__ double eps_normal(unsigned kA, unsigned kB, unsigned e)
{
  float f = bits_to_unit(rand_word(kA, kB, e));
  double u = (double)f * (2.0 - 5.9604644775390625e-8)
           - (1.0 - 5.9604644775390625e-8);
  return 1.4142135623730951 * erfinv_d(u);
}

__device__ __forceinline__ double sigd(double x) { return 1.0 / (1.0 + exp(-x)); }

__device__ __forceinline__ double gumbel_d(unsigned kA, unsigned kB, unsigned e)
{
  float f = bits_to_unit(rand_word(kA, kB, e));
  double u = (f == 0.0f) ? 1.1754943508222875e-38 : (double)f;
  return -log(-log(u));
}

// ===================== setup kernels =====================
__global__ void k_keys(unsigned* keys)
{
  if (threadIdx.x != 0 || blockIdx.x != 0) return;
  unsigned a0,a1,b0,b1,c0,c1,d0,d1;
  unsigned kx = 0u, ky = 42u;                 // jax.random.key(42)
  threefry2x32(kx, ky, 0u, 0u, a0, a1);       // carried key
  threefry2x32(kx, ky, 0u, 1u, b0, b1);       // k0 (h0 uniform)
  keys[0] = b0; keys[1] = b1;
  kx = a0; ky = a1;
  for (int s = 0; s < 100; ++s) {
    threefry2x32(kx, ky, 0u, 0u, a0, a1);     // k
    threefry2x32(kx, ky, 0u, 1u, c0, c1);     // ke
    threefry2x32(kx, ky, 0u, 2u, d0, d1);     // kr
    keys[2 + 4*s + 0] = c0; keys[2 + 4*s + 1] = c1;
    keys[2 + 4*s + 2] = d0; keys[2 + 4*s + 3] = d1;
    kx = a0; ky = a1;
  }
}

__global__ __launch_bounds__(256) void k_prep(
    const float* fcz_w, const float* fcz_b, const float* fcr_w, const float* fcr_b,
    const float* fcn_w, const float* fcn_b, const float* fco_w, const float* fco_b,
    const float* h2l_w, const float* h2l_b,
    double* wzrT, double* wnT, double* wo, double* bz, double* br,
    double* bnn, double* bo, double* h2lw, double* h2lb)
{
  int id = blockIdx.x * 256 + threadIdx.x;
  if (id < 65536) {
    int k = id >> 8, j = id & 255;
    wzrT[id] = (double)((j < 128) ? fcz_w[j*256 + k] : fcr_w[(j-128)*256 + k]);
    return;
  }
  id -= 65536;
  if (id < 65536) { int k = id >> 8, j = id & 255; wnT[id] = (double)fcn_w[j*256 + k]; return; }
  id -= 65536;
  if (id < 256) { wo[id] = (double)fco_w[id]; return; }
  id -= 256;
  if (id < 128) { bz[id] = (double)fcz_b[id]; return; }
  id -= 128;
  if (id < 128) { br[id] = (double)fcr_b[id]; return; }
  id -= 128;
  if (id < 256) { bnn[id] = (double)fcn_b[id]; return; }
  id -= 256;
  if (id < 1) { bo[0] = (double)fco_b[0]; return; }
  id -= 1;
  if (id < 384) { h2lw[id] = (double)h2l_w[id]; return; }
  id -= 384;
  if (id < 3) { h2lb[id] = (double)h2l_b[id]; return; }
}

__global__ __launch_bounds__(256) void k_h0(const unsigned* keys, double* h, double* p)
{
  unsigned e = blockIdx.x * 256 + threadIdx.x;    // < 524288
  h[e] = (double)bits_to_unit(rand_word(keys[0], keys[1], e));
  if (e < 4096) p[e] = (double)(float)log(1.0 / 128.0);
}

// ===================== frontend (map CNN encoder) =====================
__global__ __launch_bounds__(256) void k_conv1(const float* in, const float* w, double* out)
{
  int bc = blockIdx.x; int b = bc >> 4, co = bc & 15;
  __shared__ double wl[25];
  if (threadIdx.x < 25) wl[threadIdx.x] = (double)w[co*25 + threadIdx.x];
  __syncthreads();
  const float* ib = in + (size_t)b * 4096;
  for (int px = threadIdx.x; px < 1024; px += 256) {
    int oh = px >> 5, ow = px & 31;
    double acc = 0.0;
    for (int kh = 0; kh < 5; ++kh) {
      int ih = oh*2 - 2 + kh; if (ih < 0 || ih >= 64) continue;
      for (int kw = 0; kw < 5; ++kw) {
        int iw = ow*2 - 2 + kw; if (iw < 0 || iw >= 64) continue;
        acc = fma((double)ib[ih*64 + iw], wl[kh*5 + kw], acc);
      }
    }
    out[((size_t)b*16 + co)*1024 + px] = fmax(acc, 0.0);
  }
}

__global__ __launch_bounds__(256) void k_conv3x3(const double* in, const float* w,
                                                 double* out, int Ci, int Co)
{
  int bc = blockIdx.x; int b = bc / Co, co = bc % Co;
  __shared__ double wl[288];
  for (int e = threadIdx.x; e < Ci*9; e += 256) wl[e] = (double)w[co*Ci*9 + e];
  __syncthreads();
  const double* ib = in + (size_t)b * Ci * 1024;
  for (int px = threadIdx.x; px < 1024; px += 256) {
    int oh = px >> 5, ow = px & 31;
    double acc = 0.0;
    for (int ci = 0; ci < Ci; ++ci) {
      const double* ip = ib + ci*1024;
      const double* wp = wl + ci*9;
      for (int kh = 0; kh < 3; ++kh) {
        int ih = oh - 1 + kh; if (ih < 0 || ih >= 32) continue;
        for (int kw = 0; kw < 3; ++kw) {
          int iw = ow - 1 + kw; if (iw < 0 || iw >= 32) continue;
          acc = fma(ip[ih*32 + iw], wp[kh*3 + kw], acc);
        }
      }
    }
    out[((size_t)b*Co + co)*1024 + px] = fmax(acc, 0.0);
  }
}

__global__ __launch_bounds__(256) void k_bnstats(const double* x, const float* g,
                                                 const float* bta, double* scsh, int C)
{
  int c = blockIdx.x;
  double s = 0.0, s2 = 0.0;
  for (int e = threadIdx.x; e < 32*1024; e += 256) {
    int b = e >> 10, px = e & 1023;
    double v = x[((size_t)b*C + c)*1024 + px];
    s += v; s2 = fma(v, v, s2);
  }
  __shared__ double rs[256], rs2[256];
  rs[threadIdx.x] = s; rs2[threadIdx.x] = s2;
  __syncthreads();
  for (int d = 128; d; d >>= 1) {
    if (threadIdx.x < d) { rs[threadIdx.x] += rs[threadIdx.x + d]; rs2[threadIdx.x] += rs2[threadIdx.x + d]; }
    __syncthreads();
  }
  if (threadIdx.x == 0) {
    double n = 32768.0;
    double mean = rs[0] / n;
    double var = rs2[0] / n - mean*mean;
    double sc = (double)g[c] / sqrt(var + 1e-5);
    scsh[c*2] = sc;
    scsh[c*2 + 1] = (double)bta[c] - mean * sc;
  }
}

__global__ __launch_bounds__(256) void k_bnapply(double* x, const double* scsh, int C)
{
  size_t e = (size_t)blockIdx.x * 256 + threadIdx.x;
  int c = (int)((e >> 10) % (size_t)C);
  x[e] = fma(x[e], scsh[c*2], scsh[c*2 + 1]);
}

__global__ __launch_bounds__(256) void k_mapfc(const double* x, const float* w,
                                               const float* bias, double* emb)
{
  int blk = blockIdx.x; int b = blk >> 4, jg = blk & 15;
  double acc[8];
  #pragma unroll
  for (int jj = 0; jj < 8; ++jj) acc[jj] = 0.0;
  const double* xb = x + (size_t)b * 32768;
  for (int e = threadIdx.x; e < 32768; e += 256) {
    double xv = xb[e];
    #pragma unroll
    for (int jj = 0; jj < 8; ++jj)
      acc[jj] = fma(xv, (double)w[(size_t)(jg*8 + jj)*32768 + e], acc[jj]);
  }
  __shared__ double red[8][256];
  #pragma unroll
  for (int jj = 0; jj < 8; ++jj) red[jj][threadIdx.x] = acc[jj];
  __syncthreads();
  for (int d = 128; d; d >>= 1) {
    if (threadIdx.x < d)
      #pragma unroll
      for (int jj = 0; jj < 8; ++jj) red[jj][threadIdx.x] += red[jj][threadIdx.x + d];
    __syncthreads();
  }
  if (threadIdx.x < 8) {
    int j = jg*8 + threadIdx.x;
    emb[b*128 + j] = fmax(red[threadIdx.x][0] + (double)bias[j], 0.0);
  }
}

__global__ void k_maps(const double* emb, const float* m2o_w, const float* m2o_b,
                       const float* m2a_w, const float* m2a_b,
                       double* omap, double* amap)
{
  int b = blockIdx.x, j = threadIdx.x;   // 64 threads
  double a1 = (double)m2o_b[j], a2 = (double)m2a_b[j];
  for (int k = 0; k < 128; ++k) {
    double ev = emb[b*128 + k];
    a1 = fma(ev, (double)m2o_w[j*128 + k], a1);
    a2 = fma(ev, (double)m2a_w[j*128 + k], a2);
  }
  omap[b*64 + j] = fmax(a1, 0.0);
  amap[b*64 + j] = fmax(a2, 0.0);
}

__global__ __launch_bounds__(128) void k_xs(const float* obs_in, const float* act_in,
                                            const float* obs_w, const float* obs_b,
                                            const float* act_w, const float* act_b,
                                            const double* omap, const double* amap,
                                            double* xs)
{
  int s = blockIdx.x, b = blockIdx.y, j = threadIdx.x;
  double v;
  if (j < 64) {
    double a = (double)obs_b[j];
    const float* o = obs_in + ((size_t)b*100 + s)*16;
    for (int k = 0; k < 16; ++k) a = fma((double)o[k], (double)obs_w[j*16 + k], a);
    v = fmax(a, 0.0) * omap[b*64 + j];
  } else {
    int j2 = j - 64;
    double a = (double)act_b[j2];
    const float* o = act_in + ((size_t)b*100 + s)*3;
    for (int k = 0; k < 3; ++k) a = fma((double)o[k], (double)act_w[j2*3 + k], a);
    v = fmax(a, 0.0) * amap[b*64 + j2];
  }
  xs[((size_t)s*32 + b)*128 + j] = v;
}

// x-part precompute for all steps: xzr[sb][256], xn[sb][256], xo[sb]
__global__ __launch_bounds__(256) void k_xpre(const double* __restrict__ xs,
    const double* __restrict__ wzrT, const double* __restrict__ wnT,
    const double* __restrict__ wo,
    double* __restrict__ xzr, double* __restrict__ xn, double* __restrict__ xo)
{
  int sb = blockIdx.x;                 // s*32 + b
  const double* x = xs + (size_t)sb * 128;
  __shared__ double xl[128];
  __shared__ double red[128];
  int t = threadIdx.x;
  if (t < 128) xl[t] = x[t];
  __syncthreads();
  double az = 0.0, an = 0.0;
  for (int k = 0; k < 128; ++k) {
    double xv = xl[k];
    az = fma(xv, wzrT[k*256 + t], az);           // x rows 0..127 of Wzr
    an = fma(xv, wnT[(128 + k)*256 + t], an);    // x rows 128..255 of Wn
  }
  xzr[(size_t)sb*256 + t] = az;
  xn [(size_t)sb*256 + t] = an;
  if (t < 128) red[t] = xl[t] * wo[128 + t];
  __syncthreads();
  for (int d = 64; d; d >>= 1) {
    if (t < d) red[t] += red[t + d];
    __syncthreads();
  }
  if (t == 0) xo[sb] = red[0];
}

// ===================== fused scan kernels =====================
// k_step1: gather prev h via idx, pf(prev), z/rg GEMM, n GEMM, reparam,
//          h1, logpdf.  512 blocks x 128 threads, 8 rows/block.
__global__ __launch_bounds__(128) void k_step1(
    const double* __restrict__ hsrc, const int* __restrict__ idxp,
    const double* __restrict__ xzr, const double* __restrict__ xn,
    const double* __restrict__ xo,
    const double* __restrict__ wzrT, const double* __restrict__ wnT,
    const double* __restrict__ bz, const double* __restrict__ br,
    const double* __restrict__ bnn, const double* __restrict__ wo,
    const double* __restrict__ bo, const double* __restrict__ p,
    const double* __restrict__ h2lw, const double* __restrict__ h2lb,
    double* __restrict__ h1out, double* __restrict__ logpdf,
    float* __restrict__ pfout, const unsigned* __restrict__ keys, int s)
{
  __shared__ double ah[8][128];   // gathered h (= hst of step s-1)
  __shared__ double aw[8][128];   // rg*h, then h1
  const int t = threadIdx.x;
  const int r0 = blockIdx.x * 8;
  const bool first = (idxp == nullptr);
  #pragma unroll
  for (int i = 0; i < 8; ++i) {
    int r = r0 + i, b = r & 31;
    int src = first ? r : (idxp[r] * 32 + b);
    ah[i][t] = hsrc[(size_t)src * 128 + t];
  }
  __syncthreads();
  // pf for previous step (gathered rows == hst of step s-1)
  if (pfout != nullptr) {
    int wv = t >> 6, lane = t & 63;
    for (int i = wv*4; i < wv*4 + 4; ++i) {
      double v0 = ah[i][lane*2], v1 = ah[i][lane*2 + 1];
      double s0 = fma(v0, h2lw[lane*2],       v1 * h2lw[lane*2 + 1]);
      double s1 = fma(v0, h2lw[128 + lane*2], v1 * h2lw[128 + lane*2 + 1]);
      double s2 = fma(v0, h2lw[256 + lane*2], v1 * h2lw[256 + lane*2 + 1]);
      for (int d = 32; d; d >>= 1) {
        s0 += __shfl_xor(s0, d, 64);
        s1 += __shfl_xor(s1, d, 64);
        s2 += __shfl_xor(s2, d, 64);
      }
      if (lane == 0) {
        float* o = pfout + (r0 + i) * 3;
        o[0] = (float)(1.0 / (1.0 + exp(-(s0 + h2lb[0]))));
        o[1] = (float)(1.0 / (1.0 + exp(-(s1 + h2lb[1]))));
        o[2] = (float)(1.0 / (1.0 + exp(-(s2 + h2lb[2]))));
      }
    }
  }
  // GEMM1: h-part of [x|h] @ Wzr^T
  double acc0[8], acc1[8];
  #pragma unroll
  for (int i = 0; i < 8; ++i) { acc0[i] = 0.0; acc1[i] = 0.0; }
  for (int k = 0; k < 128; ++k) {
    double w0 = wzrT[(128 + k)*256 + t];
    double w1 = wzrT[(128 + k)*256 + 128 + t];
    #pragma unroll
    for (int i = 0; i < 8; ++i) {
      double av = ah[i][k];
      acc0[i] = fma(av, w0, acc0[i]);
      acc1[i] = fma(av, w1, acc1[i]);
    }
  }
  double bzv = bz[t], brv = br[t];
  double zreg[8];
  #pragma unroll
  for (int i = 0; i < 8; ++i) {
    int b = (r0 + i) & 31;
    zreg[i]   = sigd(acc0[i] + xzr[b*256 + t] + bzv);
    double rg = sigd(acc1[i] + xzr[b*256 + 128 + t] + brv);
    aw[i][t] = rg * ah[i][t];
  }
  __syncthreads();
  // GEMM2: (rg*h)-part of [rg*h|x] @ Wn^T
  #pragma unroll
  for (int i = 0; i < 8; ++i) { acc0[i] = 0.0; acc1[i] = 0.0; }
  for (int k = 0; k < 128; ++k) {
    double w0 = wnT[k*256 + t];
    double w1 = wnT[k*256 + 128 + t];
    #pragma unroll
    for (int i = 0; i < 8; ++i) {
      double av = aw[i][k];
      acc0[i] = fma(av, w0, acc0[i]);
      acc1[i] = fma(av, w1, acc1[i]);
    }
  }
  unsigned keA = keys[2 + 4*s], keB = keys[2 + 4*s + 1];
  double bn0 = bnn[t], bn1 = bnn[t + 128];
  #pragma unroll
  for (int i = 0; i < 8; ++i) {
    int r = r0 + i, b = r & 31;
    double mu  = acc0[i] + xn[b*256 + t] + bn0;
    double var = acc1[i] + xn[b*256 + 128 + t] + bn1;
    double epsn = eps_normal(keA, keB, (unsigned)(r*128 + t));
    double sp = fmax(var, 0.0) + log1p(exp(-fabs(var)));
    double n  = fma(epsn, sp, mu);
    double hv = (1.0 - zreg[i])*n + zreg[i]*ah[i][t];
    h1out[(size_t)r*128 + t] = hv;
    acc0[i] = hv;
  }
  __syncthreads();   // everyone done reading aw as rg*h
  #pragma unroll
  for (int i = 0; i < 8; ++i) aw[i][t] = acc0[i];   // now holds h1
  __syncthreads();
  // logpdf = h1 . wo[0:128] + xo[b] + bo + p
  int row = t >> 4, l16 = t & 15;
  double part = 0.0;
  for (int k = l16; k < 128; k += 16) part = fma(aw[row][k], wo[k], part);
  for (int d = 8; d; d >>= 1) part += __shfl_xor(part, d, 16);
  if (l16 == 0) {
    int r = r0 + row, b = r & 31;
    logpdf[r] = part + xo[b] + bo[0] + p[r];
  }
}

// k_sr: per-batch softmax + Gumbel-argmax resample + pn normalize + y.
// 32 blocks (one per batch) x 1024 threads (16 waves).
__global__ __launch_bounds__(1024) void k_sr(
    const double* __restrict__ logpdf, const double* __restrict__ h1,
    const unsigned* __restrict__ keys, int s,
    int* __restrict__ idx, double* __restrict__ p,
    const double* __restrict__ h2lw, const double* __restrict__ h2lb,
    float* __restrict__ yout)
{
  int b = blockIdx.x, t = threadIdx.x;
  __shared__ double p1s[128], lgs[128], pns[128], wsh[128], ys[128];
  __shared__ int    is[128];
  __shared__ double sm[2], ss[2];
  // phase 1: log_softmax over particles
  if (t < 128) {
    double v = logpdf[t*32 + b];
    double m = v;
    for (int d = 32; d; d >>= 1) m = fmax(m, __shfl_xor(m, d, 64));
    if ((t & 63) == 0) sm[t >> 6] = m;
  }
  __syncthreads();
  if (t < 128) {
    double v = logpdf[t*32 + b];
    double m = fmax(sm[0], sm[1]);
    double e = exp(v - m), su = e;
    for (int d = 32; d; d >>= 1) su += __shfl_xor(su, d, 64);
    if ((t & 63) == 0) ss[t >> 6] = su;
  }
  __syncthreads();
  if (t < 128) {
    double v = logpdf[t*32 + b];
    double m = fmax(sm[0], sm[1]);
    double p1v = v - m - log(ss[0] + ss[1]);
    p1s[t] = p1v;
    lgs[t] = log(0.5*exp(p1v) + 0.00390625);
  }
  __syncthreads();
  // phase 2: Gumbel-argmax, one draw row per wave iteration
  {
    unsigned kA = keys[2 + 4*s + 2], kB = keys[2 + 4*s + 3];
    int lane = t & 63;
    for (int i = (t >> 6); i < 128; i += 16) {
      int r = i*32 + b;
      double v0 = gumbel_d(kA, kB, (unsigned)(r*128 + lane)) + lgs[lane];
      double v1 = gumbel_d(kA, kB, (unsigned)(r*128 + lane + 64)) + lgs[lane + 64];
      double val; int bj;
      if (v0 >= v1) { val = v0; bj = lane; } else { val = v1; bj = lane + 64; }
      for (int d = 32; d; d >>= 1) {
        double ov = __shfl_xor(val, d, 64);
        int    oj = __shfl_xor(bj, d, 64);
        if (ov > val || (ov == val && oj < bj)) { val = ov; bj = oj; }
      }
      if (lane == 0) {
        is[i] = bj;
        idx[i*32 + b] = bj;                 // <-- the R3 bug: was never stored
        double pe = exp(p1s[bj]);
        pns[i] = log(pe / (0.5*pe + 0.00390625));
      }
    }
  }
  __syncthreads();
  // phase 3: normalize pn, store carry p and weights
  if (t < 128) {
    double q = pns[t];
    double m = q;
    for (int d = 32; d; d >>= 1) m = fmax(m, __shfl_xor(m, d, 64));
    if ((t & 63) == 0) sm[t >> 6] = m;
  }
  __syncthreads();
  if (t < 128) {
    double q = pns[t];
    double m = fmax(sm[0], sm[1]);
    double e = exp(q - m), su = e;
    for (int d = 32; d; d >>= 1) su += __shfl_xor(su, d, 64);
    if ((t & 63) == 0) ss[t >> 6] = su;
  }
  __syncthreads();
  if (t < 128) {
    double q = pns[t];
    double m = fmax(sm[0], sm[1]);
    double pn = q - (m + log(ss[0] + ss[1]));
    p[t*32 + b] = pn;
    wsh[t] = exp(pn);
  }
  __syncthreads();
  // phase 4: y = sum_i w_i * h1[idx_i], then h2l + sigmoid
  if (t < 128) {
    double acc = 0.0;
    for (int ii = 0; ii < 128; ++ii)
      acc = fma(wsh[ii], h1[(size_t)(is[ii]*32 + b)*128 + t], acc);
    ys[t] = acc;
  }
  __syncthreads();
  if (t < 3) {
    double d = h2lb[t];
    for (int c = 0; c < 128; ++c) d = fma(h2lw[t*128 + c], ys[c], d);
    yout[s*96 + b*3 + t] = (float)(1.0 / (1.0 + exp(-d)));
  }
}

// epilogue: pf for the last step (gather via idx)
__global__ __launch_bounds__(256) void k_pfend(const double* __restrict__ h1,
    const int* __restrict__ idx, const double* __restrict__ h2lw,
    const double* __restrict__ h2lb, float* __restrict__ pfout)
{
  int wv = threadIdx.x >> 6, lane = threadIdx.x & 63;
  int r = blockIdx.x * 4 + wv;
  int b = r & 31;
  const double* hr = h1 + (size_t)(idx[r]*32 + b) * 128;
  double v0 = hr[lane*2], v1 = hr[lane*2 + 1];
  double s0 = fma(v0, h2lw[lane*2],       v1 * h2lw[lane*2 + 1]);
  double s1 = fma(v0, h2lw[128 + lane*2], v1 * h2lw[128 + lane*2 + 1]);
  double s2 = fma(v0, h2lw[256 + lane*2], v1 * h2lw[256 + lane*2 + 1]);
  for (int d = 32; d; d >>= 1) {
    s0 += __shfl_xor(s0, d, 64);
    s1 += __shfl_xor(s1, d, 64);
    s2 += __shfl_xor(s2, d, 64);
  }
  if (lane == 0) {
    float* o = pfout + r * 3;
    o[0] = (float)(1.0 / (1.0 + exp(-(s0 + h2lb[0]))));
    o[1] = (float)(1.0 / (1.0 + exp(-(s1 + h2lb[1]))));
    o[2] = (float)(1.0 / (1.0 + exp(-(s2 + h2lb[2]))));
  }
}

// ===================== host launch =====================
extern "C" void kernel_launch(void* const* d_in, const int* in_sizes, int n_in,
                              void* d_out, int out_size, void* d_ws, size_t ws_size,
                              hipStream_t stream)
{
  (void)in_sizes; (void)n_in; (void)out_size; (void)ws_size;
  const float* map_in = (const float*)d_in[0];
  const float* obs_in = (const float*)d_in[1];
  const float* act_in = (const float*)d_in[2];
  const float* c1_w = (const float*)d_in[3];
  const float* c1_g = (const float*)d_in[4];
  const float* c1_b = (const float*)d_in[5];
  const float* c2_w = (const float*)d_in[6];
  const float* c2_g = (const float*)d_in[7];
  const float* c2_b = (const float*)d_in[8];
  const float* c3_w = (const float*)d_in[9];
  const float* c3_g = (const float*)d_in[10];
  const float* c3_b = (const float*)d_in[11];
  const float* map_w = (const float*)d_in[12];
  const float* map_b = (const float*)d_in[13];
  const float* m2o_w = (const float*)d_in[14];
  const float* m2o_b = (const float*)d_in[15];
  const float* m2a_w = (const float*)d_in[16];
  const float* m2a_b = (const float*)d_in[17];
  const float* obs_w = (const float*)d_in[18];
  const float* obs_b = (const float*)d_in[19];
  const float* act_w = (const float*)d_in[20];
  const float* act_b = (const float*)d_in[21];
  const float* fcz_w = (const float*)d_in[22];
  const float* fcz_b = (const float*)d_in[23];
  const float* fcr_w = (const float*)d_in[24];
  const float* fcr_b = (const float*)d_in[25];
  const float* fcn_w = (const float*)d_in[26];
  const float* fcn_b = (const float*)d_in[27];
  const float* fco_w = (const float*)d_in[28];
  const float* fco_b = (const float*)d_in[29];
  const float* h2l_w = (const float*)d_in[30];
  const float* h2l_b = (const float*)d_in[31];

  float* yout  = (float*)d_out;
  float* pfout = (float*)d_out + 9600;

  char* ws = (char*)d_ws;
  double*   H0     = (double*)(ws + 0);           // 4096*128
  double*   H1A    = (double*)(ws + 4194304);
  double*   H1B    = (double*)(ws + 8388608);
  double*   XS     = (double*)(ws + 12582912);    // 100*32*128
  // conv region (dead after k_mapfc) overlaid by XZR/XN/XO
  double*   C1O    = (double*)(ws + 15859712);    // 32*16*1024
  double*   C2O    = (double*)(ws + 20054016);    // 32*32*1024
  double*   C3O    = (double*)(ws + 28442624);    // 32*32*1024
  double*   XZR    = (double*)(ws + 15859712);    // 100*32*256 (overlay)
  double*   XN     = (double*)(ws + 22413312);    // 100*32*256 (overlay)
  double*   XO     = (double*)(ws + 28966912);    // 100*32     (overlay)
  double*   WZRT   = (double*)(ws + 36831232);    // 256*256
  double*   WNT    = (double*)(ws + 37355520);
  double*   WO     = (double*)(ws + 37879808);
  double*   BZ     = (double*)(ws + 37881856);
  double*   BR     = (double*)(ws + 37882880);
  double*   BNN    = (double*)(ws + 37883904);
  double*   BO     = (double*)(ws + 37885952);
  double*   H2LW   = (double*)(ws + 37886208);
  double*   H2LB   = (double*)(ws + 37889280);
  double*   EMB    = (double*)(ws + 37889536);    // 32*128
  double*   OMAP   = (double*)(ws + 37922304);    // 32*64
  double*   AMAP   = (double*)(ws + 37938688);
  double*   P      = (double*)(ws + 37955072);    // 4096
  double*   LOGPDF = (double*)(ws + 37987840);    // 4096
  int*      IDX    = (int*)   (ws + 38020608);    // 4096
  unsigned* KEYS   = (unsigned*)(ws + 38036992);  // 402
  double*   SCSH   = (double*)(ws + 38039040);    // 32*2

  // ---- setup ----
  k_keys<<<1, 64, 0, stream>>>(KEYS);
  k_prep<<<517, 256, 0, stream>>>(fcz_w, fcz_b, fcr_w, fcr_b, fcn_w, fcn_b,
                                  fco_w, fco_b, h2l_w, h2l_b,
                                  WZRT, WNT, WO, BZ, BR, BNN, BO, H2LW, H2LB);
  k_h0<<<2048, 256, 0, stream>>>(KEYS, H0, P);

  // ---- frontend ----
  k_conv1<<<512, 256, 0, stream>>>(map_in, c1_w, C1O);
  k_bnstats<<<16, 256, 0, stream>>>(C1O, c1_g, c1_b, SCSH, 16);
  k_bnapply<<<2048, 256, 0, stream>>>(C1O, SCSH, 16);
  k_conv3x3<<<1024, 256, 0, stream>>>(C1O, c2_w, C2O, 16, 32);
  k_bnstats<<<32, 256, 0, stream>>>(C2O, c2_g, c2_b, SCSH, 32);
  k_bnapply<<<4096, 256, 0, stream>>>(C2O, SCSH, 32);
  k_conv3x3<<<1024, 256, 0, stream>>>(C2O, c3_w, C3O, 32, 32);
  k_bnstats<<<32, 256, 0, stream>>>(C3O, c3_g, c3_b, SCSH, 32);
  k_bnapply<<<4096, 256, 0, stream>>>(C3O, SCSH, 32);
  k_mapfc<<<512, 256, 0, stream>>>(C3O, map_w, map_b, EMB);
  k_maps<<<32, 64, 0, stream>>>(EMB, m2o_w, m2o_b, m2a_w, m2a_b, OMAP, AMAP);
  {
    dim3 g(100, 32);
    k_xs<<<g, 128, 0, stream>>>(obs_in, act_in, obs_w, obs_b, act_w, act_b,
                                OMAP, AMAP, XS);
  }
  k_xpre<<<3200, 256, 0, stream>>>(XS, WZRT, WNT, WO, XZR, XN, XO);

  // ---- scan over 100 timesteps (2 kernels/step) ----
  double* hb[2] = { H1A, H1B };
  for (int s = 0; s < 100; ++s) {
    const double* hsrc = (s == 0) ? H0 : hb[(s - 1) & 1];
    const int* idxp = (s == 0) ? nullptr : IDX;
    float* pfprev = (s == 0) ? nullptr : (pfout + (size_t)(s - 1) * 12288);
    k_step1<<<512, 128, 0, stream>>>(hsrc, idxp,
        XZR + (size_t)s*32*256, XN + (size_t)s*32*256, XO + (size_t)s*32,
        WZRT, WNT, BZ, BR, BNN, WO, BO, P, H2LW, H2LB,
        hb[s & 1], LOGPDF, pfprev, KEYS, s);
    k_sr<<<32, 1024, 0, stream>>>(LOGPDF, hb[s & 1], KEYS, s, IDX, P,
                                  H2LW, H2LB, yout);
  }
  k_pfend<<<1024, 256, 0, stream>>>(hb[99 & 1], IDX, H2LW, H2LB,
                                    pfout + (size_t)99 * 12288);
}

// Round 5
// 9763.774 us; speedup vs baseline: 1.4320x; 1.2434x over previous
//
#include <hip/hip_runtime.h>
#include <math.h>

// ===================== JAX Threefry-2x32 (bit-exact) =====================
__device__ __forceinline__ void threefry2x32(unsigned k0, unsigned k1,
                                             unsigned x0, unsigned x1,
                                             unsigned& o0, unsigned& o1)
{
  unsigned ks2 = k0 ^ k1 ^ 0x1BD11BDAu;
  x0 += k0; x1 += k1;
#define TFR(r) { x0 += x1; x1 = (x1 << r) | (x1 >> (32 - r)); x1 ^= x0; }
  TFR(13) TFR(15) TFR(26) TFR(6)
  x0 += k1;  x1 += ks2 + 1u;
  TFR(17) TFR(29) TFR(16) TFR(24)
  x0 += ks2; x1 += k0 + 2u;
  TFR(13) TFR(15) TFR(26) TFR(6)
  x0 += k0;  x1 += k1 + 3u;
  TFR(17) TFR(29) TFR(16) TFR(24)
  x0 += k1;  x1 += ks2 + 4u;
  TFR(13) TFR(15) TFR(26) TFR(6)
  x0 += ks2; x1 += k0 + 5u;
#undef TFR
  o0 = x0; o1 = x1;
}

// jax_threefry_partitionable=True: word e = o0 ^ o1 of block (0, e)
__device__ __forceinline__ unsigned rand_word(unsigned kA, unsigned kB, unsigned e)
{
  unsigned o0, o1;
  threefry2x32(kA, kB, 0u, e, o0, o1);
  return o0 ^ o1;
}

__device__ __forceinline__ float bits_to_unit(unsigned bits)
{
  unsigned u = (bits >> 9) | 0x3f800000u;
  return __uint_as_float(u) - 1.0f;   // exact, in [0,1)
}

// erfinv in double: Giles poly init + 1 Halley iteration on erf()
__device__ __forceinline__ double erfinv_d(double x)
{
  double w = -log((1.0 - x) * (1.0 + x));
  double p;
  if (w < 5.0) {
    w -= 2.5;
    p = 2.81022636e-08;
    p = fma(p, w, 3.43273939e-07);
    p = fma(p, w, -3.5233877e-06);
    p = fma(p, w, -4.39150654e-06);
    p = fma(p, w, 0.00021858087);
    p = fma(p, w, -0.00125372503);
    p = fma(p, w, -0.00417768164);
    p = fma(p, w, 0.246640727);
    p = fma(p, w, 1.50140941);
  } else {
    w = sqrt(w) - 3.0;
    p = -0.000200214257;
    p = fma(p, w, 0.000100950558);
    p = fma(p, w, 0.00134934322);
    p = fma(p, w, -0.00367342844);
    p = fma(p, w, 0.00573950773);
    p = fma(p, w, -0.0076224613);
    p = fma(p, w, 0.00943887047);
    p = fma(p, w, 1.00167406);
    p = fma(p, w, 2.83297682);
  }
  double r = p * x;
  double f  = erf(r) - x;
  double fp = 1.1283791670955126 * exp(-r * r);   // 2/sqrt(pi) e^{-r^2}
  double q  = f / fp;
  return r - q / (1.0 + r * q);
}

// N(0,1) sample e of a jax.random.normal(f32) draw
__device__ __forceinline__ double eps_normal(unsigned kA, unsigned kB, unsigned e)
{
  float f = bits_to_unit(rand_word(kA, kB, e));
  double u = (double)f * (2.0 - 5.9604644775390625e-8)
           - (1.0 - 5.9604644775390625e-8);
  return 1.4142135623730951 * erfinv_d(u);
}

__device__ __forceinline__ double sigd(double x) { return 1.0 / (1.0 + exp(-x)); }

__device__ __forceinline__ double gumbel_d(unsigned kA, unsigned kB, unsigned e)
{
  float f = bits_to_unit(rand_word(kA, kB, e));
  double u = (f == 0.0f) ? 1.1754943508222875e-38 : (double)f;
  return -log(-log(u));
}

// ===================== setup kernels =====================
__global__ void k_keys(unsigned* keys)
{
  if (threadIdx.x != 0 || blockIdx.x != 0) return;
  unsigned a0,a1,b0,b1,c0,c1,d0,d1;
  unsigned kx = 0u, ky = 42u;                 // jax.random.key(42)
  threefry2x32(kx, ky, 0u, 0u, a0, a1);       // carried key
  threefry2x32(kx, ky, 0u, 1u, b0, b1);       // k0 (h0 uniform)
  keys[0] = b0; keys[1] = b1;
  kx = a0; ky = a1;
  for (int s = 0; s < 100; ++s) {
    threefry2x32(kx, ky, 0u, 0u, a0, a1);     // k
    threefry2x32(kx, ky, 0u, 1u, c0, c1);     // ke
    threefry2x32(kx, ky, 0u, 2u, d0, d1);     // kr
    keys[2 + 4*s + 0] = c0; keys[2 + 4*s + 1] = c1;
    keys[2 + 4*s + 2] = d0; keys[2 + 4*s + 3] = d1;
    kx = a0; ky = a1;
  }
}

__global__ __launch_bounds__(256) void k_prep(
    const float* fcz_w, const float* fcz_b, const float* fcr_w, const float* fcr_b,
    const float* fcn_w, const float* fcn_b, const float* fco_w, const float* fco_b,
    const float* h2l_w, const float* h2l_b,
    double* wzrT, double* wnT, double* wo, double* bz, double* br,
    double* bnn, double* bo, double* h2lw, double* h2lb)
{
  int id = blockIdx.x * 256 + threadIdx.x;
  if (id < 65536) {
    int k = id >> 8, j = id & 255;
    wzrT[id] = (double)((j < 128) ? fcz_w[j*256 + k] : fcr_w[(j-128)*256 + k]);
    return;
  }
  id -= 65536;
  if (id < 65536) { int k = id >> 8, j = id & 255; wnT[id] = (double)fcn_w[j*256 + k]; return; }
  id -= 65536;
  if (id < 256) { wo[id] = (double)fco_w[id]; return; }
  id -= 256;
  if (id < 128) { bz[id] = (double)fcz_b[id]; return; }
  id -= 128;
  if (id < 128) { br[id] = (double)fcr_b[id]; return; }
  id -= 128;
  if (id < 256) { bnn[id] = (double)fcn_b[id]; return; }
  id -= 256;
  if (id < 1) { bo[0] = (double)fco_b[0]; return; }
  id -= 1;
  if (id < 384) { h2lw[id] = (double)h2l_w[id]; return; }
  id -= 384;
  if (id < 3) { h2lb[id] = (double)h2l_b[id]; return; }
}

__global__ __launch_bounds__(256) void k_h0(const unsigned* keys, double* h, double* p)
{
  unsigned e = blockIdx.x * 256 + threadIdx.x;    // < 524288
  h[e] = (double)bits_to_unit(rand_word(keys[0], keys[1], e));
  if (e < 4096) p[e] = (double)(float)log(1.0 / 128.0);
}

// ===================== frontend (map CNN encoder) =====================
__global__ __launch_bounds__(256) void k_conv1(const float* in, const float* w, double* out)
{
  int bc = blockIdx.x; int b = bc >> 4, co = bc & 15;
  __shared__ double wl[25];
  __shared__ float plf[4096];
  if (threadIdx.x < 25) wl[threadIdx.x] = (double)w[co*25 + threadIdx.x];
  const float* ib = in + (size_t)b * 4096;
  for (int j = 0; j < 16; ++j) plf[threadIdx.x + j*256] = ib[threadIdx.x + j*256];
  __syncthreads();
  for (int q = 0; q < 4; ++q) {
    int px = q*256 + threadIdx.x;
    int oh = px >> 5, ow = px & 31;
    double acc = 0.0;
    for (int kh = 0; kh < 5; ++kh) {
      int ih = oh*2 - 2 + kh; if (ih < 0 || ih >= 64) continue;
      for (int kw = 0; kw < 5; ++kw) {
        int iw = ow*2 - 2 + kw; if (iw < 0 || iw >= 64) continue;
        acc = fma((double)plf[ih*64 + iw], wl[kh*5 + kw], acc);
      }
    }
    out[((size_t)b*16 + co)*1024 + px] = fmax(acc, 0.0);
  }
}

__global__ __launch_bounds__(256) void k_conv3x3(const double* in, const float* w,
                                                 double* out, int Ci, int Co)
{
  int bc = blockIdx.x; int b = bc / Co, co = bc % Co;
  __shared__ double wl[288];
  __shared__ double pl[1024];
  for (int e = threadIdx.x; e < Ci*9; e += 256) wl[e] = (double)w[co*Ci*9 + e];
  double acc[4] = {0.0, 0.0, 0.0, 0.0};
  const double* ib = in + (size_t)b * Ci * 1024;
  for (int ci = 0; ci < Ci; ++ci) {
    __syncthreads();
    for (int q = 0; q < 4; ++q)
      pl[threadIdx.x + q*256] = ib[ci*1024 + threadIdx.x + q*256];
    __syncthreads();
    const double* wp = wl + ci*9;
    for (int q = 0; q < 4; ++q) {
      int px = q*256 + threadIdx.x;
      int oh = px >> 5, ow = px & 31;
      double a = acc[q];
      for (int kh = 0; kh < 3; ++kh) {
        int ih = oh - 1 + kh; if (ih < 0 || ih >= 32) continue;
        for (int kw = 0; kw < 3; ++kw) {
          int iw = ow - 1 + kw; if (iw < 0 || iw >= 32) continue;
          a = fma(pl[ih*32 + iw], wp[kh*3 + kw], a);
        }
      }
      acc[q] = a;
    }
  }
  for (int q = 0; q < 4; ++q) {
    int px = q*256 + threadIdx.x;
    out[((size_t)b*Co + co)*1024 + px] = fmax(acc[q], 0.0);
  }
}

// BN stats, stage 1: per (c, chunk-of-4-batches) partial sums
__global__ __launch_bounds__(256) void k_bnstats1(const double* __restrict__ x,
    double* __restrict__ partS, double* __restrict__ partS2, int C)
{
  int c = blockIdx.x >> 3, chunk = blockIdx.x & 7;
  double s = 0.0, s2 = 0.0;
  for (int e = threadIdx.x; e < 4096; e += 256) {
    int b = chunk*4 + (e >> 10), px = e & 1023;
    double v = x[((size_t)b*C + c)*1024 + px];
    s += v; s2 = fma(v, v, s2);
  }
  __shared__ double rs[256], rs2[256];
  rs[threadIdx.x] = s; rs2[threadIdx.x] = s2;
  __syncthreads();
  for (int d = 128; d; d >>= 1) {
    if (threadIdx.x < d) { rs[threadIdx.x] += rs[threadIdx.x + d]; rs2[threadIdx.x] += rs2[threadIdx.x + d]; }
    __syncthreads();
  }
  if (threadIdx.x == 0) { partS[blockIdx.x] = rs[0]; partS2[blockIdx.x] = rs2[0]; }
}

// BN stats, stage 2: deterministic combine
__global__ void k_bnstats2(const double* __restrict__ partS,
                           const double* __restrict__ partS2,
                           const float* g, const float* bta, double* scsh, int C)
{
  int c = threadIdx.x;
  if (c >= C) return;
  double s = 0.0, s2 = 0.0;
  for (int j = 0; j < 8; ++j) { s += partS[c*8 + j]; s2 += partS2[c*8 + j]; }
  double n = 32768.0;
  double mean = s / n;
  double var = s2 / n - mean*mean;
  double sc = (double)g[c] / sqrt(var + 1e-5);
  scsh[c*2] = sc;
  scsh[c*2 + 1] = (double)bta[c] - mean * sc;
}

__global__ __launch_bounds__(256) void k_bnapply(double* x, const double* scsh, int C)
{
  size_t e = (size_t)blockIdx.x * 256 + threadIdx.x;
  int c = (int)((e >> 10) % (size_t)C);
  x[e] = fma(x[e], scsh[c*2], scsh[c*2 + 1]);
}

__global__ __launch_bounds__(256) void k_mapfc(const double* x, const float* w,
                                               const float* bias, double* emb)
{
  int blk = blockIdx.x; int b = blk >> 4, jg = blk & 15;
  double acc[8];
  #pragma unroll
  for (int jj = 0; jj < 8; ++jj) acc[jj] = 0.0;
  const double* xb = x + (size_t)b * 32768;
  for (int e = threadIdx.x; e < 32768; e += 256) {
    double xv = xb[e];
    #pragma unroll
    for (int jj = 0; jj < 8; ++jj)
      acc[jj] = fma(xv, (double)w[(size_t)(jg*8 + jj)*32768 + e], acc[jj]);
  }
  __shared__ double red[8][256];
  #pragma unroll
  for (int jj = 0; jj < 8; ++jj) red[jj][threadIdx.x] = acc[jj];
  __syncthreads();
  for (int d = 128; d; d >>= 1) {
    if (threadIdx.x < d)
      #pragma unroll
      for (int jj = 0; jj < 8; ++jj) red[jj][threadIdx.x] += red[jj][threadIdx.x + d];
    __syncthreads();
  }
  if (threadIdx.x < 8) {
    int j = jg*8 + threadIdx.x;
    emb[b*128 + j] = fmax(red[threadIdx.x][0] + (double)bias[j], 0.0);
  }
}

__global__ void k_maps(const double* emb, const float* m2o_w, const float* m2o_b,
                       const float* m2a_w, const float* m2a_b,
                       double* omap, double* amap)
{
  int b = blockIdx.x, j = threadIdx.x;   // 64 threads
  double a1 = (double)m2o_b[j], a2 = (double)m2a_b[j];
  for (int k = 0; k < 128; ++k) {
    double ev = emb[b*128 + k];
    a1 = fma(ev, (double)m2o_w[j*128 + k], a1);
    a2 = fma(ev, (double)m2a_w[j*128 + k], a2);
  }
  omap[b*64 + j] = fmax(a1, 0.0);
  amap[b*64 + j] = fmax(a2, 0.0);
}

// xs + xo (xo = x-part of fco dot product)
__global__ __launch_bounds__(128) void k_xs(const float* obs_in, const float* act_in,
                                            const float* obs_w, const float* obs_b,
                                            const float* act_w, const float* act_b,
                                            const double* omap, const double* amap,
                                            const double* wo,
                                            double* xs, double* xo)
{
  int s = blockIdx.x, b = blockIdx.y, j = threadIdx.x;
  double v;
  if (j < 64) {
    double a = (double)obs_b[j];
    const float* o = obs_in + ((size_t)b*100 + s)*16;
    for (int k = 0; k < 16; ++k) a = fma((double)o[k], (double)obs_w[j*16 + k], a);
    v = fmax(a, 0.0) * omap[b*64 + j];
  } else {
    int j2 = j - 64;
    double a = (double)act_b[j2];
    const float* o = act_in + ((size_t)b*100 + s)*3;
    for (int k = 0; k < 3; ++k) a = fma((double)o[k], (double)act_w[j2*3 + k], a);
    v = fmax(a, 0.0) * amap[b*64 + j2];
  }
  xs[((size_t)s*32 + b)*128 + j] = v;
  __shared__ double red[128];
  red[j] = v * wo[128 + j];
  __syncthreads();
  for (int d = 64; d; d >>= 1) {
    if (j < d) red[j] += red[j + d];
    __syncthreads();
  }
  if (j == 0) xo[s*32 + b] = red[0];
}

// x-part precompute, GEMM form: 400 blocks = (s, group-of-8-batches)
__global__ __launch_bounds__(256, 2) void k_xpre2(const double* __restrict__ xs,
    const double* __restrict__ wzrT, const double* __restrict__ wnT,
    double* __restrict__ xzr, double* __restrict__ xn)
{
  int s = blockIdx.x >> 2, bg = blockIdx.x & 3;
  __shared__ double xl[8][128];
  int t = threadIdx.x;
  #pragma unroll
  for (int j = 0; j < 4; ++j) {
    int e = t + j*256;
    int i = e >> 7, cc = e & 127;
    xl[i][cc] = xs[((size_t)s*32 + bg*8 + i)*128 + cc];
  }
  __syncthreads();
  double az[8], an[8];
  #pragma unroll
  for (int i = 0; i < 8; ++i) { az[i] = 0.0; an[i] = 0.0; }
  for (int k = 0; k < 128; ++k) {
    double wz = wzrT[k*256 + t];
    double wn = wnT[(128 + k)*256 + t];
    #pragma unroll
    for (int i = 0; i < 8; ++i) {
      double xv = xl[i][k];
      az[i] = fma(xv, wz, az[i]);
      an[i] = fma(xv, wn, an[i]);
    }
  }
  #pragma unroll
  for (int i = 0; i < 8; ++i) {
    size_t sb = (size_t)s*32 + bg*8 + i;
    xzr[sb*256 + t] = az[i];
    xn [sb*256 + t] = an[i];
  }
}

// ===================== fused scan kernels =====================
// k_step1: 256 blocks x 512 threads; 16 rows/block; thread = (rg = t>>8
// row-subgroup of 8, c = t&255 output column). All operand exchange via LDS.
__global__ __launch_bounds__(512, 2) void k_step1(
    const double* __restrict__ hsrc, const int* __restrict__ idxp,
    const double* __restrict__ xzr, const double* __restrict__ xn,
    const double* __restrict__ xo,
    const double* __restrict__ wzrT, const double* __restrict__ wnT,
    const double* __restrict__ bz, const double* __restrict__ br,
    const double* __restrict__ bnn, const double* __restrict__ wo,
    const double* __restrict__ bo, const double* __restrict__ p,
    const double* __restrict__ h2lw, const double* __restrict__ h2lb,
    double* __restrict__ h1out, double* __restrict__ logpdf,
    float* __restrict__ pfout, const unsigned* __restrict__ keys, int s)
{
  __shared__ double ah[16][128];   // gathered h (= hst of step s-1)
  __shared__ double aw[16][128];   // rg*h, later eps
  __shared__ double zsh[16][128];  // z, later h1
  __shared__ double sps[16][128];  // softplus(var)
  const int t  = threadIdx.x;
  const int rg = t >> 8;           // 0/1: rows rg*8 .. rg*8+7
  const int c  = t & 255;          // output column 0..255
  const int r0 = blockIdx.x * 16;
  const bool first = (idxp == nullptr);
  // gather prev h (4 elements/thread, coalesced rows)
  #pragma unroll
  for (int j = 0; j < 4; ++j) {
    int e = t + j*512;
    int r = e >> 7, cc = e & 127;
    int R = r0 + r, b = R & 31;
    int src = first ? R : (idxp[R]*32 + b);
    ah[r][cc] = hsrc[(size_t)src*128 + cc];
  }
  __syncthreads();
  // pf for previous step: 8 waves x 2 rows
  if (pfout != nullptr) {
    int wv = t >> 6, lane = t & 63;
    #pragma unroll
    for (int q = 0; q < 2; ++q) {
      int i = wv*2 + q;
      double v0 = ah[i][lane*2], v1 = ah[i][lane*2 + 1];
      double s0 = fma(v0, h2lw[lane*2],       v1 * h2lw[lane*2 + 1]);
      double s1 = fma(v0, h2lw[128 + lane*2], v1 * h2lw[128 + lane*2 + 1]);
      double s2 = fma(v0, h2lw[256 + lane*2], v1 * h2lw[256 + lane*2 + 1]);
      for (int d = 32; d; d >>= 1) {
        s0 += __shfl_xor(s0, d, 64);
        s1 += __shfl_xor(s1, d, 64);
        s2 += __shfl_xor(s2, d, 64);
      }
      if (lane == 0) {
        float* o = pfout + (r0 + i) * 3;
        o[0] = (float)(1.0 / (1.0 + exp(-(s0 + h2lb[0]))));
        o[1] = (float)(1.0 / (1.0 + exp(-(s1 + h2lb[1]))));
        o[2] = (float)(1.0 / (1.0 + exp(-(s2 + h2lb[2]))));
      }
    }
  }
  // GEMM1: h-part of [x|h] @ Wzr^T  (col c; 8 rows)
  double acc[8];
  #pragma unroll
  for (int i = 0; i < 8; ++i) acc[i] = 0.0;
  for (int k = 0; k < 128; ++k) {
    double w = wzrT[(128 + k)*256 + c];
    #pragma unroll
    for (int i = 0; i < 8; ++i) acc[i] = fma(ah[rg*8 + i][k], w, acc[i]);
  }
  if (c < 128) {               // z columns
    double bzv = bz[c];
    #pragma unroll
    for (int i = 0; i < 8; ++i) {
      int b = (r0 + rg*8 + i) & 31;
      zsh[rg*8 + i][c] = sigd(acc[i] + xzr[b*256 + c] + bzv);
    }
  } else {                     // rg columns -> aw = rg*h
    int cc = c - 128;
    double brv = br[cc];
    #pragma unroll
    for (int i = 0; i < 8; ++i) {
      int b = (r0 + rg*8 + i) & 31;
      double rgv = sigd(acc[i] + xzr[b*256 + c] + brv);
      aw[rg*8 + i][cc] = rgv * ah[rg*8 + i][cc];
    }
  }
  __syncthreads();
  // GEMM2: (rg*h)-part of [rg*h|x] @ Wn^T
  #pragma unroll
  for (int i = 0; i < 8; ++i) acc[i] = 0.0;
  for (int k = 0; k < 128; ++k) {
    double w = wnT[k*256 + c];
    #pragma unroll
    for (int i = 0; i < 8; ++i) acc[i] = fma(aw[rg*8 + i][k], w, acc[i]);
  }
  // finish mu / softplus(var) in registers
  double mv[8];
  if (c < 128) {               // mu columns
    double bn0 = bnn[c];
    #pragma unroll
    for (int i = 0; i < 8; ++i) {
      int b = (r0 + rg*8 + i) & 31;
      mv[i] = acc[i] + xn[b*256 + c] + bn0;
    }
  } else {                     // var columns -> softplus
    double bn1 = bnn[c];
    #pragma unroll
    for (int i = 0; i < 8; ++i) {
      int b = (r0 + rg*8 + i) & 31;
      double var = acc[i] + xn[b*256 + c] + bn1;
      mv[i] = fmax(var, 0.0) + log1p(exp(-fabs(var)));
    }
  }
  __syncthreads();   // all aw reads (GEMM2) complete
  if (c >= 128) {
    int cc = c - 128;
    #pragma unroll
    for (int i = 0; i < 8; ++i) sps[rg*8 + i][cc] = mv[i];
  }
  // eps: distributed over all 512 threads (4 each), into aw
  {
    unsigned keA = keys[2 + 4*s], keB = keys[2 + 4*s + 1];
    #pragma unroll
    for (int j = 0; j < 4; ++j) {
      int e = t + j*512;
      int r = e >> 7, cc = e & 127;
      aw[r][cc] = eps_normal(keA, keB, (unsigned)((r0 + r)*128 + cc));
    }
  }
  __syncthreads();
  // h1 = (1-z)*n + z*h  (mu threads), write global + keep in zsh
  if (c < 128) {
    #pragma unroll
    for (int i = 0; i < 8; ++i) {
      int row = rg*8 + i, R = r0 + row;
      double n  = fma(aw[row][c], sps[row][c], mv[i]);
      double z  = zsh[row][c];
      double hv = (1.0 - z)*n + z*ah[row][c];
      h1out[(size_t)R*128 + c] = hv;
      zsh[row][c] = hv;
    }
  }
  __syncthreads();
  // logpdf: 8 waves x 2 rows
  {
    int wv = t >> 6, lane = t & 63;
    #pragma unroll
    for (int q = 0; q < 2; ++q) {
      int row = wv*2 + q, R = r0 + row, b = R & 31;
      double part = fma(zsh[row][lane], wo[lane], zsh[row][lane + 64] * wo[lane + 64]);
      for (int d = 32; d; d >>= 1) part += __shfl_xor(part, d, 64);
      if (lane == 0) logpdf[R] = part + xo[b] + bo[0] + p[R];
    }
  }
}

// k_sr: per-batch softmax + Gumbel-argmax resample + pn normalize + y.
__global__ __launch_bounds__(1024) void k_sr(
    const double* __restrict__ logpdf, const double* __restrict__ h1,
    const unsigned* __restrict__ keys, int s,
    int* __restrict__ idx, double* __restrict__ p,
    const double* __restrict__ h2lw, const double* __restrict__ h2lb,
    float* __restrict__ yout)
{
  int b = blockIdx.x, t = threadIdx.x;
  __shared__ double p1s[128], lgs[128], pns[128], wsh[128], ys[128];
  __shared__ int    is[128];
  __shared__ double sm[2], ss[2];
  // phase 1: log_softmax over particles
  if (t < 128) {
    double v = logpdf[t*32 + b];
    double m = v;
    for (int d = 32; d; d >>= 1) m = fmax(m, __shfl_xor(m, d, 64));
    if ((t & 63) == 0) sm[t >> 6] = m;
  }
  __syncthreads();
  if (t < 128) {
    double v = logpdf[t*32 + b];
    double m = fmax(sm[0], sm[1]);
    double e = exp(v - m), su = e;
    for (int d = 32; d; d >>= 1) su += __shfl_xor(su, d, 64);
    if ((t & 63) == 0) ss[t >> 6] = su;
  }
  __syncthreads();
  if (t < 128) {
    double v = logpdf[t*32 + b];
    double m = fmax(sm[0], sm[1]);
    double p1v = v - m - log(ss[0] + ss[1]);
    p1s[t] = p1v;
    lgs[t] = log(0.5*exp(p1v) + 0.00390625);
  }
  __syncthreads();
  // phase 2: Gumbel-argmax, one draw row per wave iteration
  {
    unsigned kA = keys[2 + 4*s + 2], kB = keys[2 + 4*s + 3];
    int lane = t & 63;
    for (int i = (t >> 6); i < 128; i += 16) {
      int r = i*32 + b;
      double v0 = gumbel_d(kA, kB, (unsigned)(r*128 + lane)) + lgs[lane];
      double v1 = gumbel_d(kA, kB, (unsigned)(r*128 + lane + 64)) + lgs[lane + 64];
      double val; int bj;
      if (v0 >= v1) { val = v0; bj = lane; } else { val = v1; bj = lane + 64; }
      for (int d = 32; d; d >>= 1) {
        double ov = __shfl_xor(val, d, 64);
        int    oj = __shfl_xor(bj, d, 64);
        if (ov > val || (ov == val && oj < bj)) { val = ov; bj = oj; }
      }
      if (lane == 0) {
        is[i] = bj;
        idx[i*32 + b] = bj;
        double pe = exp(p1s[bj]);
        pns[i] = log(pe / (0.5*pe + 0.00390625));
      }
    }
  }
  __syncthreads();
  // phase 3: normalize pn, store carry p and weights
  if (t < 128) {
    double q = pns[t];
    double m = q;
    for (int d = 32; d; d >>= 1) m = fmax(m, __shfl_xor(m, d, 64));
    if ((t & 63) == 0) sm[t >> 6] = m;
  }
  __syncthreads();
  if (t < 128) {
    double q = pns[t];
    double m = fmax(sm[0], sm[1]);
    double e = exp(q - m), su = e;
    for (int d = 32; d; d >>= 1) su += __shfl_xor(su, d, 64);
    if ((t & 63) == 0) ss[t >> 6] = su;
  }
  __syncthreads();
  if (t < 128) {
    double q = pns[t];
    double m = fmax(sm[0], sm[1]);
    double pn = q - (m + log(ss[0] + ss[1]));
    p[t*32 + b] = pn;
    wsh[t] = exp(pn);
  }
  __syncthreads();
  // phase 4: y = sum_i w_i * h1[idx_i], then h2l + sigmoid
  if (t < 128) {
    double acc = 0.0;
    for (int ii = 0; ii < 128; ++ii)
      acc = fma(wsh[ii], h1[(size_t)(is[ii]*32 + b)*128 + t], acc);
    ys[t] = acc;
  }
  __syncthreads();
  if (t < 3) {
    double d = h2lb[t];
    for (int c = 0; c < 128; ++c) d = fma(h2lw[t*128 + c], ys[c], d);
    yout[s*96 + b*3 + t] = (float)(1.0 / (1.0 + exp(-d)));
  }
}

// epilogue: pf for the last step (gather via idx)
__global__ __launch_bounds__(256) void k_pfend(const double* __restrict__ h1,
    const int* __restrict__ idx, const double* __restrict__ h2lw,
    const double* __restrict__ h2lb, float* __restrict__ pfout)
{
  int wv = threadIdx.x >> 6, lane = threadIdx.x & 63;
  int r = blockIdx.x * 4 + wv;
  int b = r & 31;
  const double* hr = h1 + (size_t)(idx[r]*32 + b) * 128;
  double v0 = hr[lane*2], v1 = hr[lane*2 + 1];
  double s0 = fma(v0, h2lw[lane*2],       v1 * h2lw[lane*2 + 1]);
  double s1 = fma(v0, h2lw[128 + lane*2], v1 * h2lw[128 + lane*2 + 1]);
  double s2 = fma(v0, h2lw[256 + lane*2], v1 * h2lw[256 + lane*2 + 1]);
  for (int d = 32; d; d >>= 1) {
    s0 += __shfl_xor(s0, d, 64);
    s1 += __shfl_xor(s1, d, 64);
    s2 += __shfl_xor(s2, d, 64);
  }
  if (lane == 0) {
    float* o = pfout + r * 3;
    o[0] = (float)(1.0 / (1.0 + exp(-(s0 + h2lb[0]))));
    o[1] = (float)(1.0 / (1.0 + exp(-(s1 + h2lb[1]))));
    o[2] = (float)(1.0 / (1.0 + exp(-(s2 + h2lb[2]))));
  }
}

// ===================== host launch =====================
extern "C" void kernel_launch(void* const* d_in, const int* in_sizes, int n_in,
                              void* d_out, int out_size, void* d_ws, size_t ws_size,
                              hipStream_t stream)
{
  (void)in_sizes; (void)n_in; (void)out_size; (void)ws_size;
  const float* map_in = (const float*)d_in[0];
  const float* obs_in = (const float*)d_in[1];
  const float* act_in = (const float*)d_in[2];
  const float* c1_w = (const float*)d_in[3];
  const float* c1_g = (const float*)d_in[4];
  const float* c1_b = (const float*)d_in[5];
  const float* c2_w = (const float*)d_in[6];
  const float* c2_g = (const float*)d_in[7];
  const float* c2_b = (const float*)d_in[8];
  const float* c3_w = (const float*)d_in[9];
  const float* c3_g = (const float*)d_in[10];
  const float* c3_b = (const float*)d_in[11];
  const float* map_w = (const float*)d_in[12];
  const float* map_b = (const float*)d_in[13];
  const float* m2o_w = (const float*)d_in[14];
  const float* m2o_b = (const float*)d_in[15];
  const float* m2a_w = (const float*)d_in[16];
  const float* m2a_b = (const float*)d_in[17];
  const float* obs_w = (const float*)d_in[18];
  const float* obs_b = (const float*)d_in[19];
  const float* act_w = (const float*)d_in[20];
  const float* act_b = (const float*)d_in[21];
  const float* fcz_w = (const float*)d_in[22];
  const float* fcz_b = (const float*)d_in[23];
  const float* fcr_w = (const float*)d_in[24];
  const float* fcr_b = (const float*)d_in[25];
  const float* fcn_w = (const float*)d_in[26];
  const float* fcn_b = (const float*)d_in[27];
  const float* fco_w = (const float*)d_in[28];
  const float* fco_b = (const float*)d_in[29];
  const float* h2l_w = (const float*)d_in[30];
  const float* h2l_b = (const float*)d_in[31];

  float* yout  = (float*)d_out;
  float* pfout = (float*)d_out + 9600;

  char* ws = (char*)d_ws;
  double*   H0     = (double*)(ws + 0);           // 4096*128
  double*   H1A    = (double*)(ws + 4194304);
  double*   H1B    = (double*)(ws + 8388608);
  double*   XS     = (double*)(ws + 12582912);    // 100*32*128
  // conv region (dead after k_mapfc) overlaid by XZR/XN/XO
  double*   C1O    = (double*)(ws + 15859712);    // 32*16*1024
  double*   C2O    = (double*)(ws + 20054016);    // 32*32*1024
  double*   C3O    = (double*)(ws + 28442624);    // 32*32*1024
  double*   XZR    = (double*)(ws + 15859712);    // 100*32*256 (overlay)
  double*   XN     = (double*)(ws + 22413312);    // 100*32*256 (overlay)
  double*   XO     = (double*)(ws + 28966912);    // 100*32     (overlay)
  double*   WZRT   = (double*)(ws + 36831232);    // 256*256
  double*   WNT    = (double*)(ws + 37355520);
  double*   WO     = (double*)(ws + 37879808);
  double*   BZ     = (double*)(ws + 37881856);
  double*   BR     = (double*)(ws + 37882880);
  double*   BNN    = (double*)(ws + 37883904);
  double*   BO     = (double*)(ws + 37885952);
  double*   H2LW   = (double*)(ws + 37886208);
  double*   H2LB   = (double*)(ws + 37889280);
  double*   EMB    = (double*)(ws + 37889536);    // 32*128
  double*   OMAP   = (double*)(ws + 37922304);    // 32*64
  double*   AMAP   = (double*)(ws + 37938688);
  double*   P      = (double*)(ws + 37955072);    // 4096
  double*   LOGPDF = (double*)(ws + 37987840);    // 4096
  int*      IDX    = (int*)   (ws + 38020608);    // 4096
  unsigned* KEYS   = (unsigned*)(ws + 38036992);  // 402
  double*   SCSH   = (double*)(ws + 38039040);    // 32*2
  double*   PARTS  = (double*)(ws + 38039552);    // 256
  double*   PARTS2 = (double*)(ws + 38041600);    // 256

  // ---- setup ----
  k_keys<<<1, 64, 0, stream>>>(KEYS);
  k_prep<<<517, 256, 0, stream>>>(fcz_w, fcz_b, fcr_w, fcr_b, fcn_w, fcn_b,
                                  fco_w, fco_b, h2l_w, h2l_b,
                                  WZRT, WNT, WO, BZ, BR, BNN, BO, H2LW, H2LB);
  k_h0<<<2048, 256, 0, stream>>>(KEYS, H0, P);

  // ---- frontend ----
  k_conv1<<<512, 256, 0, stream>>>(map_in, c1_w, C1O);
  k_bnstats1<<<128, 256, 0, stream>>>(C1O, PARTS, PARTS2, 16);
  k_bnstats2<<<1, 32, 0, stream>>>(PARTS, PARTS2, c1_g, c1_b, SCSH, 16);
  k_bnapply<<<2048, 256, 0, stream>>>(C1O, SCSH, 16);
  k_conv3x3<<<1024, 256, 0, stream>>>(C1O, c2_w, C2O, 16, 32);
  k_bnstats1<<<256, 256, 0, stream>>>(C2O, PARTS, PARTS2, 32);
  k_bnstats2<<<1, 32, 0, stream>>>(PARTS, PARTS2, c2_g, c2_b, SCSH, 32);
  k_bnapply<<<4096, 256, 0, stream>>>(C2O, SCSH, 32);
  k_conv3x3<<<1024, 256, 0, stream>>>(C2O, c3_w, C3O, 32, 32);
  k_bnstats1<<<256, 256, 0, stream>>>(C3O, PARTS, PARTS2, 32);
  k_bnstats2<<<1, 32, 0, stream>>>(PARTS, PARTS2, c3_g, c3_b, SCSH, 32);
  k_bnapply<<<4096, 256, 0, stream>>>(C3O, SCSH, 32);
  k_mapfc<<<512, 256, 0, stream>>>(C3O, map_w, map_b, EMB);
  k_maps<<<32, 64, 0, stream>>>(EMB, m2o_w, m2o_b, m2a_w, m2a_b, OMAP, AMAP);
  {
    dim3 g(100, 32);
    k_xs<<<g, 128, 0, stream>>>(obs_in, act_in, obs_w, obs_b, act_w, act_b,
                                OMAP, AMAP, WO, XS, XO);
  }
  k_xpre2<<<400, 256, 0, stream>>>(XS, WZRT, WNT, XZR, XN);

  // ---- scan over 100 timesteps (2 kernels/step) ----
  double* hb[2] = { H1A, H1B };
  for (int s = 0; s < 100; ++s) {
    const double* hsrc = (s == 0) ? H0 : hb[(s - 1) & 1];
    const int* idxp = (s == 0) ? nullptr : IDX;
    float* pfprev = (s == 0) ? nullptr : (pfout + (size_t)(s - 1) * 12288);
    k_step1<<<256, 512, 0, stream>>>(hsrc, idxp,
        XZR + (size_t)s*32*256, XN + (size_t)s*32*256, XO + (size_t)s*32,
        WZRT, WNT, BZ, BR, BNN, WO, BO, P, H2LW, H2LB,
        hb[s & 1], LOGPDF, pfprev, KEYS, s);
    k_sr<<<32, 1024, 0, stream>>>(LOGPDF, hb[s & 1], KEYS, s, IDX, P,
                                  H2LW, H2LB, yout);
  }
  k_pfend<<<1024, 256, 0, stream>>>(hb[99 & 1], IDX, H2LW, H2LB,
                                    pfout + (size_t)99 * 12288);
}